// Round 3
// baseline (806.532 us; speedup 1.0000x reference)
//
#include <hip/hip_runtime.h>
#include <hip/hip_bf16.h>
#include <stdint.h>

#define NNODES 50000
#define NEDGES 800000
#define HC 256

typedef unsigned short u16;
typedef __attribute__((ext_vector_type(8))) short bf16x8;
typedef __attribute__((ext_vector_type(4))) float f32x4;

__device__ __forceinline__ float b2f(u16 v) {
    return __uint_as_float(((unsigned)v) << 16);
}
__device__ __forceinline__ u16 f2b(float f) {
    unsigned u = __float_as_uint(f);
    u += 0x7fff + ((u >> 16) & 1);
    return (u16)(u >> 16);
}

// param table: W1,atts1,attd1,We1,atte1,b1,g1,be1,W2,atts2,attd2,We2,atte2,b2,g2,be2,Wout,bout
__device__ __constant__ int dPO[19] = {0,16384,16640,16896,20992,21248,21504,21760,22016,
                                       87552,87808,88064,92160,92416,92672,92928,93184,93440,93441};
static const int hPO[19] = {0,16384,16640,16896,20992,21248,21504,21760,22016,
                            87552,87808,88064,92160,92416,92672,92928,93184,93440,93441};
#define TOTP 93441

__global__ void zero_init(unsigned* __restrict__ p, long nwords) {
    long i = (long)blockIdx.x * blockDim.x + threadIdx.x;
    long stride = (long)gridDim.x * blockDim.x;
    for (; i < nwords; i += stride) p[i] = 0u;
}

// 1 = bf16 inputs, 0 = fp32 inputs
__global__ void detect_dtype(const unsigned* __restrict__ xbits, int* __restrict__ flag) {
    __shared__ int cnt;
    if (threadIdx.x == 0) cnt = 0;
    __syncthreads();
    int sane = 0;
    for (int i = threadIdx.x; i < 1024; i += 256) {
        unsigned lo = xbits[i] & 0xffffu;
        int e = (int)((lo >> 7) & 0xff);
        if (e >= 117 && e <= 133) sane++;
    }
    atomicAdd(&cnt, sane);
    __syncthreads();
    if (threadIdx.x == 0) *flag = (cnt >= 512) ? 1 : 0;
}

__global__ void cvt_bf16(const void* __restrict__ src, u16* __restrict__ dst, int n,
                         const int* __restrict__ flag) {
    int isbf16 = *flag;
    int i = blockIdx.x * 256 + threadIdx.x;
    int stride = gridDim.x * 256;
    if (isbf16) {
        const u16* s = (const u16*)src;
        for (; i < n; i += stride) dst[i] = s[i];
    } else {
        const float* s = (const float*)src;
        for (; i < n; i += stride) dst[i] = f2b(s[i]);
    }
}

struct Ptrs18 { const void* s[18]; };
__global__ void cvt_params(Ptrs18 p, u16* __restrict__ dst, const int* __restrict__ flag) {
    int i = blockIdx.x * 256 + threadIdx.x;
    if (i >= TOTP) return;
    int isbf16 = *flag;
    int idx = 0;
    #pragma unroll
    for (int j = 1; j < 18; j++) idx += (i >= dPO[j]) ? 1 : 0;
    int rel = i - dPO[idx];
    dst[i] = isbf16 ? ((const u16*)p.s[idx])[rel] : f2b(((const float*)p.s[idx])[rel]);
}

__global__ void proj_weight(const u16* __restrict__ W, const u16* __restrict__ att,
                            float* __restrict__ out, int R) {
    int i = blockIdx.x * 256 + threadIdx.x;
    if (i >= R * 4) return;
    int f = i >> 2, h = i & 3;
    float s = 0.f;
    for (int c = 0; c < 64; c++)
        s += b2f(W[f * 256 + h * 64 + c]) * b2f(att[h * 64 + c]);
    out[i] = s;
}

__global__ void proj_weight2(const u16* __restrict__ W, const u16* __restrict__ atta,
                             const u16* __restrict__ attb,
                             float* __restrict__ outa, float* __restrict__ outb, int R) {
    int i = blockIdx.x * 256 + threadIdx.x;
    if (i >= R * 4) return;
    int f = i >> 2, h = i & 3;
    float sa = 0.f, sb = 0.f;
    for (int c = 0; c < 64; c++) {
        float w = b2f(W[f * 256 + h * 64 + c]);
        sa += w * b2f(atta[h * 64 + c]);
        sb += w * b2f(attb[h * 64 + c]);
    }
    outa[i] = sa;
    outb[i] = sb;
}

// W[K][256] -> WT[256][K]
__global__ void transpose_w(const u16* __restrict__ W, u16* __restrict__ WT, int K) {
    int i = blockIdx.x * 256 + threadIdx.x;
    if (i >= K * 256) return;
    int k = i / 256, c = i % 256;
    WT[c * K + k] = W[i];
}

// ---------------- degree histogram ----------------
__global__ void edge_deg(const int* __restrict__ edst, int* __restrict__ deg) {
    int e = blockIdx.x * 256 + threadIdx.x;
    if (e >= NEDGES) return;
    atomicAdd(&deg[edst[e]], 1);
}

// ---------------- CSR scan ----------------
__global__ void block_sum(const int* __restrict__ deg, int* __restrict__ bsums, int n) {
    __shared__ int lds[256];
    int i = blockIdx.x * 256 + threadIdx.x;
    lds[threadIdx.x] = (i < n) ? deg[i] : 0;
    __syncthreads();
    for (int s = 128; s; s >>= 1) {
        if (threadIdx.x < s) lds[threadIdx.x] += lds[threadIdx.x + s];
        __syncthreads();
    }
    if (threadIdx.x == 0) bsums[blockIdx.x] = lds[0];
}

__global__ void scan_bsums(const int* __restrict__ bsums, int* __restrict__ boffs, int nb) {
    __shared__ int lds[256];
    int t = threadIdx.x;
    int v = (t < nb) ? bsums[t] : 0;
    lds[t] = v;
    __syncthreads();
    for (int s = 1; s < 256; s <<= 1) {
        int u = (t >= s) ? lds[t - s] : 0;
        __syncthreads();
        lds[t] += u;
        __syncthreads();
    }
    boffs[t] = lds[t] - v;  // exclusive
}

__global__ void write_offsets(const int* __restrict__ deg, const int* __restrict__ boffs,
                              int* __restrict__ off, int* __restrict__ cursor, int n) {
    __shared__ int lds[256];
    int t = threadIdx.x;
    int i = blockIdx.x * 256 + t;
    int v = (i < n) ? deg[i] : 0;
    lds[t] = v;
    __syncthreads();
    for (int s = 1; s < 256; s <<= 1) {
        int u = (t >= s) ? lds[t - s] : 0;
        __syncthreads();
        lds[t] += u;
        __syncthreads();
    }
    int exc = lds[t] - v + boffs[blockIdx.x];
    if (i < n) { off[i] = exc; cursor[i] = exc; }
}

// ---------------- edge stage: per-layer 16B records + dense src, scattered once ----------------
__global__ __launch_bounds__(256) void edge_stage(
    const void* __restrict__ eattr_raw, const int* __restrict__ flag,
    const int* __restrict__ esrc, const int* __restrict__ edst,
    const float* __restrict__ ve1, const float* __restrict__ ve2,
    int* __restrict__ cursor, uint4* __restrict__ rec1, uint4* __restrict__ rec2,
    int* __restrict__ src_csr) {
    int e = blockIdx.x * 256 + threadIdx.x;
    if (e >= NEDGES) return;
    float a[16];
    if (*flag) {
        const u16* s = (const u16*)eattr_raw + (long)e * 16;
        const uint4* q = (const uint4*)s;
        uint4 q0 = q[0], q1 = q[1];
        unsigned w0[8] = {q0.x, q0.y, q0.z, q0.w, q1.x, q1.y, q1.z, q1.w};
        #pragma unroll
        for (int j = 0; j < 8; j++) {
            a[2 * j] = b2f((u16)(w0[j] & 0xffff));
            a[2 * j + 1] = b2f((u16)(w0[j] >> 16));
        }
    } else {
        const float* s = (const float*)eattr_raw + (long)e * 16;
        #pragma unroll
        for (int j = 0; j < 16; j += 4) {
            float4 q = *(const float4*)(s + j);
            a[j] = q.x; a[j + 1] = q.y; a[j + 2] = q.z; a[j + 3] = q.w;
        }
    }
    float s1[4], s2[4];
    #pragma unroll
    for (int h = 0; h < 4; h++) {
        float t1 = 0.f, t2 = 0.f;
        #pragma unroll
        for (int f = 0; f < 16; f++) {
            t1 += a[f] * ve1[f * 4 + h];
            t2 += a[f] * ve2[f * 4 + h];
        }
        s1[h] = t1;
        s2[h] = t2;
    }
    unsigned a1lo = (unsigned)f2b(s1[0]) | ((unsigned)f2b(s1[1]) << 16);
    unsigned a1hi = (unsigned)f2b(s1[2]) | ((unsigned)f2b(s1[3]) << 16);
    unsigned a2lo = (unsigned)f2b(s2[0]) | ((unsigned)f2b(s2[1]) << 16);
    unsigned a2hi = (unsigned)f2b(s2[2]) | ((unsigned)f2b(s2[3]) << 16);
    int d = edst[e];
    int p = atomicAdd(&cursor[d], 1);
    unsigned src = (unsigned)esrc[e];
    rec1[p] = make_uint4(src, a1lo, a1hi, 0u);
    rec2[p] = make_uint4(src, a2lo, a2hi, 0u);
    src_csr[p] = (int)src;
}

// ---------------- BN coefficient finalize: y = v*coef[c] + coef[256+c] ----------------
__global__ void bn_coef(const float* __restrict__ stats, const u16* __restrict__ g,
                        const u16* __restrict__ be, float* __restrict__ coef) {
    int c = threadIdx.x;  // 256
    float mu = stats[c] * (1.0f / NNODES);
    float var = stats[256 + c] * (1.0f / NNODES) - mu * mu;
    var = fmaxf(var, 0.f);
    float rs = rsqrtf(var + 1e-5f);
    float sc = b2f(g[c]) * rs;
    coef[c] = sc;
    coef[256 + c] = b2f(be[c]) - sc * mu;
}

// ---------------- in-place BN+ReLU apply on [NNODES][256] bf16 ----------------
__global__ __launch_bounds__(256) void bn_apply(u16* __restrict__ h,
                                                const float* __restrict__ coef) {
    long i = (long)blockIdx.x * 256 + threadIdx.x;  // octet index (8 bf16)
    long total = (long)NNODES * (HC / 8);
    long stride = (long)gridDim.x * 256;
    int cpos = (int)(i & 31) * 8;
    float scl[8], shf[8];
    #pragma unroll
    for (int j = 0; j < 8; j++) {
        scl[j] = coef[cpos + j];
        shf[j] = coef[256 + cpos + j];
    }
    for (; i < total; i += stride) {
        uint4 v = *((const uint4*)h + i);
        unsigned w[4] = {v.x, v.y, v.z, v.w};
        #pragma unroll
        for (int q = 0; q < 4; q++) {
            float lo = b2f((u16)(w[q] & 0xffffu));
            float hi = b2f((u16)(w[q] >> 16));
            lo = fmaxf(lo * scl[2 * q] + shf[2 * q], 0.f);
            hi = fmaxf(hi * scl[2 * q + 1] + shf[2 * q + 1], 0.f);
            w[q] = (unsigned)f2b(lo) | ((unsigned)f2b(hi) << 16);
        }
        *((uint4*)h + i) = make_uint4(w[0], w[1], w[2], w[3]);
    }
}

// ---------------- tiled MFMA GEMM: C[M x 256] = A[M x K] * WT[256 x K]^T ----------------
__device__ __forceinline__ void gload_lds16(const u16* g, u16* l) {
    __builtin_amdgcn_global_load_lds(
        (const __attribute__((address_space(1))) unsigned*)g,
        (__attribute__((address_space(3))) unsigned*)l, 16, 0, 0);
}

template <int K>
__global__ __launch_bounds__(256) void gemm_tile(const u16* __restrict__ A,
                                                 const u16* __restrict__ WT,
                                                 u16* __restrict__ out) {
    __shared__ u16 As[128 * 32];  // [row][32] 64B rows
    __shared__ u16 Bs[128 * 32];
    int tid = threadIdx.x;
    int wave = tid >> 6, lane = tid & 63;
    int wr = wave >> 1, wc = wave & 1;
    int quad = lane >> 4, l15 = lane & 15;
    long row0 = (long)(blockIdx.x >> 1) * 128;
    int col0 = (blockIdx.x & 1) * 128;
    int srow = lane >> 2;        // 0..15: row within 16-row staging chunk
    int soct = (lane & 3) * 8;   // element offset within 32-elem row
    f32x4 acc[4][4] = {};
    for (int kk = 0; kk < K; kk += 32) {
        #pragma unroll
        for (int sub = 0; sub < 2; sub++) {
            int rr = wave * 32 + sub * 16;   // wave-uniform chunk base row
            long gr = row0 + rr + srow;
            if (gr >= NNODES) gr = NNODES - 1;  // clamp: read valid, store predicated
            gload_lds16(A + gr * K + kk + soct, &As[rr * 32]);
            gload_lds16(WT + (long)(col0 + rr + srow) * K + kk + soct, &Bs[rr * 32]);
        }
        __syncthreads();
        bf16x8 av[4], bv[4];
        #pragma unroll
        for (int m = 0; m < 4; m++)
            av[m] = *(const bf16x8*)&As[(wr * 64 + m * 16 + l15) * 32 + quad * 8];
        #pragma unroll
        for (int n = 0; n < 4; n++)
            bv[n] = *(const bf16x8*)&Bs[(wc * 64 + n * 16 + l15) * 32 + quad * 8];
        #pragma unroll
        for (int m = 0; m < 4; m++)
            #pragma unroll
            for (int n = 0; n < 4; n++)
                acc[m][n] = __builtin_amdgcn_mfma_f32_16x16x32_bf16(av[m], bv[n],
                                                                    acc[m][n], 0, 0, 0);
        __syncthreads();
    }
    #pragma unroll
    for (int m = 0; m < 4; m++) {
        #pragma unroll
        for (int j = 0; j < 4; j++) {
            long r = row0 + wr * 64 + m * 16 + quad * 4 + j;
            if (r < NNODES) {
                u16* op = out + r * HC + col0 + wc * 64 + l15;
                #pragma unroll
                for (int n = 0; n < 4; n++) op[n * 16] = f2b(acc[m][n][j]);
            }
        }
    }
}

// ---------------- a_s/a_d projection ----------------
template <int K, bool BN>
__global__ __launch_bounds__(256) void proj_att(const u16* __restrict__ X,
                                                const float* __restrict__ coef,
                                                const float* __restrict__ us,
                                                const float* __restrict__ ud,
                                                float* __restrict__ as_, float* __restrict__ ad_) {
    int wid = (blockIdx.x * 256 + threadIdx.x) >> 6;
    int lane = threadIdx.x & 63;
    if (wid >= NNODES) return;
    float pas[4] = {0.f, 0.f, 0.f, 0.f}, pad[4] = {0.f, 0.f, 0.f, 0.f};
    const u16* row = X + (long)wid * K;
    for (int f = lane; f < K; f += 64) {
        float xv = b2f(row[f]);
        if (BN) xv = fmaxf(xv * coef[f] + coef[256 + f], 0.f);
        #pragma unroll
        for (int h = 0; h < 4; h++) {
            pas[h] += xv * us[f * 4 + h];
            pad[h] += xv * ud[f * 4 + h];
        }
    }
    #pragma unroll
    for (int h = 0; h < 4; h++) {
        for (int o = 32; o; o >>= 1) {
            pas[h] += __shfl_down(pas[h], o);
            pad[h] += __shfl_down(pad[h], o);
        }
    }
    if (lane == 0) {
        #pragma unroll
        for (int h = 0; h < 4; h++) {
            as_[wid * 4 + h] = pas[h];
            ad_[wid * 4 + h] = pad[h];
        }
    }
}

// ---------------- GAT attention pass: normalized alpha (f32, per head) + wself ----------------
// af layout: af[h * NEDGES + slot]; wselfp: [N*4]
__global__ __launch_bounds__(256) void gat_attn(
    const float* __restrict__ as_, const float* __restrict__ ad_,
    const uint4* __restrict__ recl,
    const int* __restrict__ off, const int* __restrict__ deg,
    float* __restrict__ af, float* __restrict__ wselfp) {
    __shared__ float w_lds[4][64][4];
    int wid = (blockIdx.x * 256 + threadIdx.x) >> 6;
    if (wid >= NNODES) return;
    int wave = threadIdx.x >> 6;
    int lane = threadIdx.x & 63;
    int d = wid;
    int st = off[d], dg = deg[d];
    int slot = lane >> 2, h = lane & 3;
    float adv = ad_[d * 4 + h];
    float m = -1e30f, s = 0.f, sae = 0.f;
    const uint4* rbase = recl + st;

    if (dg <= 64) {
        for (int i = slot; i < dg; i += 16) {
            uint4 r4 = rbase[i];
            int src = (int)r4.x;
            unsigned wsel = (h & 2) ? r4.z : r4.y;
            float aev = b2f((u16)((h & 1) ? (wsel >> 16) : (wsel & 0xffffu)));
            float t = as_[src * 4 + h] + adv + aev;
            float lg = (t > 0.f) ? t : 0.2f * t;
            w_lds[wave][i][h] = lg;
            sae += aev;
            float mn = fmaxf(m, lg);
            s = s * __expf(m - mn) + __expf(lg - mn);
            m = mn;
        }
        #pragma unroll
        for (int o = 4; o < 64; o <<= 1) {
            float mo = __shfl_xor(m, o), so = __shfl_xor(s, o), ao = __shfl_xor(sae, o);
            float mn = fmaxf(m, mo);
            s = s * __expf(m - mn) + so * __expf(mo - mn);
            m = mn;
            sae += ao;
        }
        float invs, wself;
        {
            float asv = as_[d * 4 + h];
            float l0 = asv + adv + sae / fmaxf((float)dg, 1.f);
            l0 = (l0 > 0.f) ? l0 : 0.2f * l0;
            float mn = fmaxf(m, l0);
            s = s * __expf(m - mn) + __expf(l0 - mn);
            m = mn;
            invs = 1.f / s;
            wself = __expf(l0 - mn) * invs;
        }
        if (slot == 0) wselfp[d * 4 + h] = wself;
        for (int i = slot; i < dg; i += 16)
            af[h * NEDGES + st + i] = __expf(w_lds[wave][i][h] - m) * invs;
        return;
    }

    // ---------- fallback (deg > 64): streaming, exact ----------
    for (int base = 0; base < dg; base += 16) {
        int i = base + slot;
        float lg = -1e30f, aev = 0.f, w = 0.f;
        if (i < dg) {
            uint4 r4 = rbase[i];
            int src = (int)r4.x;
            unsigned wsel = (h & 2) ? r4.z : r4.y;
            aev = b2f((u16)((h & 1) ? (wsel >> 16) : (wsel & 0xffffu)));
            float t = as_[src * 4 + h] + adv + aev;
            lg = (t > 0.f) ? t : 0.2f * t;
        }
        sae += aev;
        float mn = fmaxf(m, lg);
        if (i < dg) w = __expf(lg - mn);
        s = s * __expf(m - mn) + w;
        m = mn;
    }
    #pragma unroll
    for (int o = 4; o < 64; o <<= 1) {
        float mo = __shfl_xor(m, o), so = __shfl_xor(s, o), ao = __shfl_xor(sae, o);
        float mn = fmaxf(m, mo);
        s = s * __expf(m - mn) + so * __expf(mo - mn);
        m = mn;
        sae += ao;
    }
    float invs, wself;
    {
        float asv = as_[d * 4 + h];
        float l0 = asv + adv + sae / fmaxf((float)dg, 1.f);
        l0 = (l0 > 0.f) ? l0 : 0.2f * l0;
        float mn = fmaxf(m, l0);
        s = s * __expf(m - mn) + __expf(l0 - mn);
        m = mn;
        invs = 1.f / s;
        wself = __expf(l0 - mn) * invs;
    }
    if (slot == 0) wselfp[d * 4 + h] = wself;
    for (int i = slot; i < dg; i += 16) {
        uint4 r4 = rbase[i];
        int src = (int)r4.x;
        unsigned wsel = (h & 2) ? r4.z : r4.y;
        float aev = b2f((u16)((h & 1) ? (wsel >> 16) : (wsel & 0xffffu)));
        float t = as_[src * 4 + h] + adv + aev;
        t = (t > 0.f) ? t : 0.2f * t;
        af[h * NEDGES + st + i] = __expf(t - m) * invs;
    }
}

// ---------------- GAT gather pass: column-sliced, XCD-pinned (slice = blockIdx%8) ------
// slice = 32 cols = 64 B per row; per-XCD working set of xs = 3.2 MB (< 4 MB L2).
// One wave per dst per slice; 4 x 16-lane groups process 4 edges in parallel.
__global__ __launch_bounds__(256) void gat_gather(
    const u16* __restrict__ xs, const float* __restrict__ af,
    const float* __restrict__ wselfp, const int* __restrict__ src_csr,
    const int* __restrict__ off, const int* __restrict__ deg,
    const u16* __restrict__ bias, u16* __restrict__ out) {
    int b = blockIdx.x;
    int slice = b & 7;
    int dgrp = b >> 3;
    int wave = threadIdx.x >> 6, lane = threadIdx.x & 63;
    int d = dgrp * 4 + wave;  // 12500 dgrps * 4 = 50000 exactly
    int g = lane >> 4, l15 = lane & 15;
    int hd = slice >> 1;
    int c0 = slice * 32 + l15 * 2;
    int st = off[d], dg = deg[d];
    const float* afh = af + (long)hd * NEDGES + st;
    const int* sc = src_csr + st;
    const u16* xcol = xs + c0;
    float a0, a1;
    {
        float wsf = (g == 0) ? wselfp[d * 4 + hd] : 0.f;
        unsigned v = *(const unsigned*)(xcol + (long)d * HC);
        a0 = wsf * b2f((u16)(v & 0xffffu));
        a1 = wsf * b2f((u16)(v >> 16));
    }
    int i = g;
    for (; i + 12 < dg; i += 16) {
        int s0 = sc[i], s1 = sc[i + 4], s2 = sc[i + 8], s3 = sc[i + 12];
        float w0 = afh[i], w1 = afh[i + 4], w2 = afh[i + 8], w3 = afh[i + 12];
        unsigned v0 = *(const unsigned*)(xcol + (long)s0 * HC);
        unsigned v1 = *(const unsigned*)(xcol + (long)s1 * HC);
        unsigned v2 = *(const unsigned*)(xcol + (long)s2 * HC);
        unsigned v3 = *(const unsigned*)(xcol + (long)s3 * HC);
        a0 += w0 * b2f((u16)(v0 & 0xffffu)) + w1 * b2f((u16)(v1 & 0xffffu))
            + w2 * b2f((u16)(v2 & 0xffffu)) + w3 * b2f((u16)(v3 & 0xffffu));
        a1 += w0 * b2f((u16)(v0 >> 16)) + w1 * b2f((u16)(v1 >> 16))
            + w2 * b2f((u16)(v2 >> 16)) + w3 * b2f((u16)(v3 >> 16));
    }
    for (; i < dg; i += 4) {
        int s0 = sc[i];
        float w0 = afh[i];
        unsigned v0 = *(const unsigned*)(xcol + (long)s0 * HC);
        a0 += w0 * b2f((u16)(v0 & 0xffffu));
        a1 += w0 * b2f((u16)(v0 >> 16));
    }
    a0 += __shfl_xor(a0, 16); a1 += __shfl_xor(a1, 16);
    a0 += __shfl_xor(a0, 32); a1 += __shfl_xor(a1, 32);
    if (g == 0) {
        unsigned bv = *(const unsigned*)(bias + c0);
        a0 += b2f((u16)(bv & 0xffffu));
        a1 += b2f((u16)(bv >> 16));
        unsigned ov = (unsigned)f2b(a0) | ((unsigned)f2b(a1) << 16);
        *(unsigned*)(out + (long)d * HC + c0) = ov;
    }
}

// ---------------- BatchNorm stats ----------------
__global__ void bn_stats(const u16* __restrict__ h, float* __restrict__ stats) {
    int c = threadIdx.x;
    float s = 0.f, q = 0.f;
    for (int r = blockIdx.x; r < NNODES; r += gridDim.x) {
        float v = b2f(h[(long)r * HC + c]);
        s += v;
        q += v * v;
    }
    atomicAdd(&stats[c], s);
    atomicAdd(&stats[256 + c], q);
}

// ---------------- output head (+fused BN2+ReLU) ----------------
__global__ __launch_bounds__(256) void out_head(const u16* __restrict__ h,
                                                const float* __restrict__ coef,
                                                const u16* __restrict__ wout,
                                                const u16* __restrict__ bout,
                                                void* __restrict__ y,
                                                const int* __restrict__ flag) {
    int wid = (blockIdx.x * 256 + threadIdx.x) >> 6;
    int lane = threadIdx.x & 63;
    if (wid >= NNODES) return;
    const u16* r = h + (long)wid * HC + lane * 4;
    int c0 = lane * 4;
    float p = 0.f;
    #pragma unroll
    for (int j = 0; j < 4; j++) {
        float v = b2f(r[j]);
        v = fmaxf(v * coef[c0 + j] + coef[256 + c0 + j], 0.f);
        p += v * b2f(wout[c0 + j]);
    }
    for (int o = 32; o; o >>= 1) p += __shfl_down(p, o);
    if (lane == 0) {
        float v = p + b2f(bout[0]);
        if (*flag) ((u16*)y)[wid] = f2b(v);
        else       ((float*)y)[wid] = v;
    }
}

extern "C" void kernel_launch(void* const* d_in, const int* in_sizes, int n_in,
                              void* d_out, int out_size, void* d_ws, size_t ws_size,
                              hipStream_t stream) {
    (void)in_sizes; (void)n_in; (void)out_size; (void)ws_size;
    const void* x_raw     = d_in[0];
    const int*  esrc      = (const int*)d_in[1];
    const int*  edst      = (const int*)d_in[2];
    const void* eattr_raw = d_in[3];

    char* ws = (char*)d_ws;
    size_t o = 0;
    auto alloc = [&](size_t bytes) -> char* {
        o = (o + 255) & ~(size_t)255;
        char* p = ws + o;
        o += bytes;
        return p;
    };
    int* dflag = (int*)alloc(256);
    u16* xb   = (u16*)alloc((size_t)NNODES * 64 * 2);
    u16* pall = (u16*)alloc((size_t)TOTP * 2);
    u16 *W1b = pall + hPO[0], *atts1b = pall + hPO[1], *attd1b = pall + hPO[2],
        *We1b = pall + hPO[3], *atte1b = pall + hPO[4], *b1b = pall + hPO[5],
        *g1b = pall + hPO[6], *be1b = pall + hPO[7], *W2b = pall + hPO[8],
        *atts2b = pall + hPO[9], *attd2b = pall + hPO[10], *We2b = pall + hPO[11],
        *atte2b = pall + hPO[12], *b2b = pall + hPO[13], *g2b = pall + hPO[14],
        *be2b = pall + hPO[15], *Woutb = pall + hPO[16], *boutb = pall + hPO[17];
    u16* WT1 = (u16*)alloc(256 * 64 * 2);
    u16* WT2 = (u16*)alloc(256 * 256 * 2);
    float* ve1 = (float*)alloc(64 * 4);
    float* ve2 = (float*)alloc(64 * 4);
    float* us1 = (float*)alloc(256 * 4);
    float* ud1 = (float*)alloc(256 * 4);
    float* us2 = (float*)alloc(1024 * 4);
    float* ud2 = (float*)alloc(1024 * 4);
    float* coef1 = (float*)alloc(512 * 4);
    float* coef2 = (float*)alloc(512 * 4);
    // zero zone: deg + stats
    int* deg = (int*)alloc((size_t)NNODES * 4);
    float* stats1 = (float*)alloc(512 * 4);
    float* stats2 = (float*)alloc(512 * 4);
    size_t zero_end = o;
    size_t zero_begin = (size_t)((char*)deg - ws);
    // rest
    int* off = (int*)alloc((size_t)NNODES * 4);
    int* cursor = (int*)alloc((size_t)NNODES * 4);
    int* bsums = (int*)alloc(256 * 4);
    int* boffs = (int*)alloc(256 * 4);
    uint4* rec1 = (uint4*)alloc((size_t)NEDGES * 16);
    uint4* rec2 = (uint4*)alloc((size_t)NEDGES * 16);
    int* src_csr = (int*)alloc((size_t)NEDGES * 4);
    float* af = (float*)alloc((size_t)4 * NEDGES * 4);
    float* wselfp = (float*)alloc((size_t)NNODES * 16);
    float* as_ = (float*)alloc((size_t)NNODES * 16);
    float* ad_ = (float*)alloc((size_t)NNODES * 16);
    u16* bufA = (u16*)alloc((size_t)NNODES * HC * 2);  // xs1, then xs2
    u16* bufB = (u16*)alloc((size_t)NNODES * HC * 2);  // h1raw, then h2raw

    long zwords = (long)((zero_end - zero_begin) / 4);
    zero_init<<<128, 256, 0, stream>>>((unsigned*)(ws + zero_begin), zwords);
    detect_dtype<<<1, 256, 0, stream>>>((const unsigned*)x_raw, dflag);

    cvt_bf16<<<2048, 256, 0, stream>>>(x_raw, xb, NNODES * 64, dflag);
    Ptrs18 pp;
    for (int i = 0; i < 18; i++) pp.s[i] = d_in[4 + i];
    cvt_params<<<(TOTP + 255) / 256, 256, 0, stream>>>(pp, pall, dflag);

    transpose_w<<<64, 256, 0, stream>>>(W1b, WT1, 64);
    transpose_w<<<256, 256, 0, stream>>>(W2b, WT2, 256);
    proj_weight<<<1, 256, 0, stream>>>(We1b, atte1b, ve1, 16);
    proj_weight<<<1, 256, 0, stream>>>(We2b, atte2b, ve2, 16);
    proj_weight2<<<1, 256, 0, stream>>>(W1b, atts1b, attd1b, us1, ud1, 64);
    proj_weight2<<<4, 256, 0, stream>>>(W2b, atts2b, attd2b, us2, ud2, 256);

    int eblocks = (NEDGES + 255) / 256;
    int nb = (NNODES + 255) / 256;  // 196
    edge_deg<<<eblocks, 256, 0, stream>>>(edst, deg);
    block_sum<<<nb, 256, 0, stream>>>(deg, bsums, NNODES);
    scan_bsums<<<1, 256, 0, stream>>>(bsums, boffs, nb);
    write_offsets<<<nb, 256, 0, stream>>>(deg, boffs, off, cursor, NNODES);
    edge_stage<<<eblocks, 256, 0, stream>>>(eattr_raw, dflag, esrc, edst, ve1, ve2,
                                            cursor, rec1, rec2, src_csr);

    int gtiles = ((NNODES + 127) / 128) * 2;  // 782
    int wblocks = (NNODES * 64 + 255) / 256;  // 12500
    int gblocks = (NNODES / 4) * 8;           // 100000

    // layer 1 (xb: K=64)
    gemm_tile<64><<<gtiles, 256, 0, stream>>>(xb, WT1, bufA);
    proj_att<64, false><<<wblocks, 256, 0, stream>>>(xb, nullptr, us1, ud1, as_, ad_);
    gat_attn<<<wblocks, 256, 0, stream>>>(as_, ad_, rec1, off, deg, af, wselfp);
    gat_gather<<<gblocks, 256, 0, stream>>>(bufA, af, wselfp, src_csr, off, deg, b1b, bufB);
    bn_stats<<<512, 256, 0, stream>>>(bufB, stats1);
    bn_coef<<<1, 256, 0, stream>>>(stats1, g1b, be1b, coef1);

    // layer 2: materialize ReLU(BN1(h1)) in place, then plain GEMM + proj
    bn_apply<<<2048, 256, 0, stream>>>(bufB, coef1);
    gemm_tile<256><<<gtiles, 256, 0, stream>>>(bufB, WT2, bufA);
    proj_att<256, false><<<wblocks, 256, 0, stream>>>(bufB, nullptr, us2, ud2, as_, ad_);
    gat_attn<<<wblocks, 256, 0, stream>>>(as_, ad_, rec2, off, deg, af, wselfp);
    gat_gather<<<gblocks, 256, 0, stream>>>(bufA, af, wselfp, src_csr, off, deg, b2b, bufB);
    bn_stats<<<512, 256, 0, stream>>>(bufB, stats2);
    bn_coef<<<1, 256, 0, stream>>>(stats2, g2b, be2b, coef2);

    // output head (BN2 fused)
    out_head<<<wblocks, 256, 0, stream>>>(bufB, coef2, Woutb, boutb, d_out, dflag);
}

// Round 4
// 546.709 us; speedup vs baseline: 1.4752x; 1.4752x over previous
//
#include <hip/hip_runtime.h>
#include <hip/hip_bf16.h>
#include <stdint.h>

#define NNODES 50000
#define NEDGES 800000
#define HC 256

typedef unsigned short u16;
typedef __attribute__((ext_vector_type(8))) short bf16x8;
typedef __attribute__((ext_vector_type(4))) float f32x4;

__device__ __forceinline__ float b2f(u16 v) {
    return __uint_as_float(((unsigned)v) << 16);
}
__device__ __forceinline__ u16 f2b(float f) {
    unsigned u = __float_as_uint(f);
    u += 0x7fff + ((u >> 16) & 1);
    return (u16)(u >> 16);
}

// param table: W1,atts1,attd1,We1,atte1,b1,g1,be1,W2,atts2,attd2,We2,atte2,b2,g2,be2,Wout,bout
__device__ __constant__ int dPO[19] = {0,16384,16640,16896,20992,21248,21504,21760,22016,
                                       87552,87808,88064,92160,92416,92672,92928,93184,93440,93441};
static const int hPO[19] = {0,16384,16640,16896,20992,21248,21504,21760,22016,
                            87552,87808,88064,92160,92416,92672,92928,93184,93440,93441};
#define TOTP 93441

__global__ void zero_init(unsigned* __restrict__ p, long nwords) {
    long i = (long)blockIdx.x * blockDim.x + threadIdx.x;
    long stride = (long)gridDim.x * blockDim.x;
    for (; i < nwords; i += stride) p[i] = 0u;
}

// 1 = bf16 inputs, 0 = fp32 inputs
__global__ void detect_dtype(const unsigned* __restrict__ xbits, int* __restrict__ flag) {
    __shared__ int cnt;
    if (threadIdx.x == 0) cnt = 0;
    __syncthreads();
    int sane = 0;
    for (int i = threadIdx.x; i < 1024; i += 256) {
        unsigned lo = xbits[i] & 0xffffu;
        int e = (int)((lo >> 7) & 0xff);
        if (e >= 117 && e <= 133) sane++;
    }
    atomicAdd(&cnt, sane);
    __syncthreads();
    if (threadIdx.x == 0) *flag = (cnt >= 512) ? 1 : 0;
}

__global__ void cvt_bf16(const void* __restrict__ src, u16* __restrict__ dst, int n,
                         const int* __restrict__ flag) {
    int isbf16 = *flag;
    int i = blockIdx.x * 256 + threadIdx.x;
    int stride = gridDim.x * 256;
    if (isbf16) {
        const u16* s = (const u16*)src;
        for (; i < n; i += stride) dst[i] = s[i];
    } else {
        const float* s = (const float*)src;
        for (; i < n; i += stride) dst[i] = f2b(s[i]);
    }
}

struct Ptrs18 { const void* s[18]; };
__global__ void cvt_params(Ptrs18 p, u16* __restrict__ dst, const int* __restrict__ flag) {
    int i = blockIdx.x * 256 + threadIdx.x;
    if (i >= TOTP) return;
    int isbf16 = *flag;
    int idx = 0;
    #pragma unroll
    for (int j = 1; j < 18; j++) idx += (i >= dPO[j]) ? 1 : 0;
    int rel = i - dPO[idx];
    dst[i] = isbf16 ? ((const u16*)p.s[idx])[rel] : f2b(((const float*)p.s[idx])[rel]);
}

__global__ void proj_weight(const u16* __restrict__ W, const u16* __restrict__ att,
                            float* __restrict__ out, int R) {
    int i = blockIdx.x * 256 + threadIdx.x;
    if (i >= R * 4) return;
    int f = i >> 2, h = i & 3;
    float s = 0.f;
    for (int c = 0; c < 64; c++)
        s += b2f(W[f * 256 + h * 64 + c]) * b2f(att[h * 64 + c]);
    out[i] = s;
}

__global__ void proj_weight2(const u16* __restrict__ W, const u16* __restrict__ atta,
                             const u16* __restrict__ attb,
                             float* __restrict__ outa, float* __restrict__ outb, int R) {
    int i = blockIdx.x * 256 + threadIdx.x;
    if (i >= R * 4) return;
    int f = i >> 2, h = i & 3;
    float sa = 0.f, sb = 0.f;
    for (int c = 0; c < 64; c++) {
        float w = b2f(W[f * 256 + h * 64 + c]);
        sa += w * b2f(atta[h * 64 + c]);
        sb += w * b2f(attb[h * 64 + c]);
    }
    outa[i] = sa;
    outb[i] = sb;
}

// W[K][256] -> WT[256][K]
__global__ void transpose_w(const u16* __restrict__ W, u16* __restrict__ WT, int K) {
    int i = blockIdx.x * 256 + threadIdx.x;
    if (i >= K * 256) return;
    int k = i / 256, c = i % 256;
    WT[c * K + k] = W[i];
}

// ---------------- degree histogram ----------------
__global__ void edge_deg(const int* __restrict__ edst, int* __restrict__ deg) {
    int e = blockIdx.x * 256 + threadIdx.x;
    if (e >= NEDGES) return;
    atomicAdd(&deg[edst[e]], 1);
}

// ---------------- CSR scan ----------------
__global__ void block_sum(const int* __restrict__ deg, int* __restrict__ bsums, int n) {
    __shared__ int lds[256];
    int i = blockIdx.x * 256 + threadIdx.x;
    lds[threadIdx.x] = (i < n) ? deg[i] : 0;
    __syncthreads();
    for (int s = 128; s; s >>= 1) {
        if (threadIdx.x < s) lds[threadIdx.x] += lds[threadIdx.x + s];
        __syncthreads();
    }
    if (threadIdx.x == 0) bsums[blockIdx.x] = lds[0];
}

__global__ void scan_bsums(const int* __restrict__ bsums, int* __restrict__ boffs, int nb) {
    __shared__ int lds[256];
    int t = threadIdx.x;
    int v = (t < nb) ? bsums[t] : 0;
    lds[t] = v;
    __syncthreads();
    for (int s = 1; s < 256; s <<= 1) {
        int u = (t >= s) ? lds[t - s] : 0;
        __syncthreads();
        lds[t] += u;
        __syncthreads();
    }
    boffs[t] = lds[t] - v;  // exclusive
}

__global__ void write_offsets(const int* __restrict__ deg, const int* __restrict__ boffs,
                              int* __restrict__ off, int* __restrict__ cursor, int n) {
    __shared__ int lds[256];
    int t = threadIdx.x;
    int i = blockIdx.x * 256 + t;
    int v = (i < n) ? deg[i] : 0;
    lds[t] = v;
    __syncthreads();
    for (int s = 1; s < 256; s <<= 1) {
        int u = (t >= s) ? lds[t - s] : 0;
        __syncthreads();
        lds[t] += u;
        __syncthreads();
    }
    int exc = lds[t] - v + boffs[blockIdx.x];
    if (i < n) { off[i] = exc; cursor[i] = exc; }
}

// ---------------- edge stage: one 32B record per edge, scattered once ----------------
__global__ __launch_bounds__(256) void edge_stage(
    const void* __restrict__ eattr_raw, const int* __restrict__ flag,
    const int* __restrict__ esrc, const int* __restrict__ edst,
    const float* __restrict__ ve1, const float* __restrict__ ve2,
    int* __restrict__ cursor, uint4* __restrict__ rec) {
    int e = blockIdx.x * 256 + threadIdx.x;
    if (e >= NEDGES) return;
    float a[16];
    if (*flag) {
        const u16* s = (const u16*)eattr_raw + (long)e * 16;
        const uint4* q = (const uint4*)s;
        uint4 q0 = q[0], q1 = q[1];
        unsigned w0[8] = {q0.x, q0.y, q0.z, q0.w, q1.x, q1.y, q1.z, q1.w};
        #pragma unroll
        for (int j = 0; j < 8; j++) {
            a[2 * j] = b2f((u16)(w0[j] & 0xffff));
            a[2 * j + 1] = b2f((u16)(w0[j] >> 16));
        }
    } else {
        const float* s = (const float*)eattr_raw + (long)e * 16;
        #pragma unroll
        for (int j = 0; j < 16; j += 4) {
            float4 q = *(const float4*)(s + j);
            a[j] = q.x; a[j + 1] = q.y; a[j + 2] = q.z; a[j + 3] = q.w;
        }
    }
    float s1[4], s2[4];
    #pragma unroll
    for (int h = 0; h < 4; h++) {
        float t1 = 0.f, t2 = 0.f;
        #pragma unroll
        for (int f = 0; f < 16; f++) {
            t1 += a[f] * ve1[f * 4 + h];
            t2 += a[f] * ve2[f * 4 + h];
        }
        s1[h] = t1;
        s2[h] = t2;
    }
    unsigned a1lo = (unsigned)f2b(s1[0]) | ((unsigned)f2b(s1[1]) << 16);
    unsigned a1hi = (unsigned)f2b(s1[2]) | ((unsigned)f2b(s1[3]) << 16);
    unsigned a2lo = (unsigned)f2b(s2[0]) | ((unsigned)f2b(s2[1]) << 16);
    unsigned a2hi = (unsigned)f2b(s2[2]) | ((unsigned)f2b(s2[3]) << 16);
    int d = edst[e];
    int p = atomicAdd(&cursor[d], 1);
    unsigned src = (unsigned)esrc[e];
    rec[(long)p * 2 + 0] = make_uint4(src, a1lo, a1hi, 0u);
    rec[(long)p * 2 + 1] = make_uint4(src, a2lo, a2hi, 0u);
}

// ---------------- BN coefficient finalize: y = v*coef[c] + coef[256+c] ----------------
__global__ void bn_coef(const float* __restrict__ stats, const u16* __restrict__ g,
                        const u16* __restrict__ be, float* __restrict__ coef) {
    int c = threadIdx.x;  // 256
    float mu = stats[c] * (1.0f / NNODES);
    float var = stats[256 + c] * (1.0f / NNODES) - mu * mu;
    var = fmaxf(var, 0.f);
    float rs = rsqrtf(var + 1e-5f);
    float sc = b2f(g[c]) * rs;
    coef[c] = sc;
    coef[256 + c] = b2f(be[c]) - sc * mu;
}

// ---------------- in-place BN+ReLU apply on [NNODES][256] bf16 ----------------
__global__ __launch_bounds__(256) void bn_apply(u16* __restrict__ h,
                                                const float* __restrict__ coef) {
    long i = (long)blockIdx.x * 256 + threadIdx.x;  // octet index (8 bf16)
    long total = (long)NNODES * (HC / 8);
    long stride = (long)gridDim.x * 256;
    int cpos = (int)(i & 31) * 8;
    float scl[8], shf[8];
    #pragma unroll
    for (int j = 0; j < 8; j++) {
        scl[j] = coef[cpos + j];
        shf[j] = coef[256 + cpos + j];
    }
    for (; i < total; i += stride) {
        uint4 v = *((const uint4*)h + i);
        unsigned w[4] = {v.x, v.y, v.z, v.w};
        #pragma unroll
        for (int q = 0; q < 4; q++) {
            float lo = b2f((u16)(w[q] & 0xffffu));
            float hi = b2f((u16)(w[q] >> 16));
            lo = fmaxf(lo * scl[2 * q] + shf[2 * q], 0.f);
            hi = fmaxf(hi * scl[2 * q + 1] + shf[2 * q + 1], 0.f);
            w[q] = (unsigned)f2b(lo) | ((unsigned)f2b(hi) << 16);
        }
        *((uint4*)h + i) = make_uint4(w[0], w[1], w[2], w[3]);
    }
}

// ---------------- tiled MFMA GEMM: C[M x 256] = A[M x K] * WT[256 x K]^T ----------------
__device__ __forceinline__ void gload_lds16(const u16* g, u16* l) {
    __builtin_amdgcn_global_load_lds(
        (const __attribute__((address_space(1))) unsigned*)g,
        (__attribute__((address_space(3))) unsigned*)l, 16, 0, 0);
}

template <int K>
__global__ __launch_bounds__(256) void gemm_tile(const u16* __restrict__ A,
                                                 const u16* __restrict__ WT,
                                                 u16* __restrict__ out) {
    __shared__ u16 As[128 * 32];  // [row][32] 64B rows
    __shared__ u16 Bs[128 * 32];
    int tid = threadIdx.x;
    int wave = tid >> 6, lane = tid & 63;
    int wr = wave >> 1, wc = wave & 1;
    int quad = lane >> 4, l15 = lane & 15;
    long row0 = (long)(blockIdx.x >> 1) * 128;
    int col0 = (blockIdx.x & 1) * 128;
    int srow = lane >> 2;        // 0..15: row within 16-row staging chunk
    int soct = (lane & 3) * 8;   // element offset within 32-elem row
    f32x4 acc[4][4] = {};
    for (int kk = 0; kk < K; kk += 32) {
        #pragma unroll
        for (int sub = 0; sub < 2; sub++) {
            int rr = wave * 32 + sub * 16;   // wave-uniform chunk base row
            long gr = row0 + rr + srow;
            if (gr >= NNODES) gr = NNODES - 1;  // clamp: read valid, store predicated
            gload_lds16(A + gr * K + kk + soct, &As[rr * 32]);
            gload_lds16(WT + (long)(col0 + rr + srow) * K + kk + soct, &Bs[rr * 32]);
        }
        __syncthreads();
        bf16x8 av[4], bv[4];
        #pragma unroll
        for (int m = 0; m < 4; m++)
            av[m] = *(const bf16x8*)&As[(wr * 64 + m * 16 + l15) * 32 + quad * 8];
        #pragma unroll
        for (int n = 0; n < 4; n++)
            bv[n] = *(const bf16x8*)&Bs[(wc * 64 + n * 16 + l15) * 32 + quad * 8];
        #pragma unroll
        for (int m = 0; m < 4; m++)
            #pragma unroll
            for (int n = 0; n < 4; n++)
                acc[m][n] = __builtin_amdgcn_mfma_f32_16x16x32_bf16(av[m], bv[n],
                                                                    acc[m][n], 0, 0, 0);
        __syncthreads();
    }
    #pragma unroll
    for (int m = 0; m < 4; m++) {
        #pragma unroll
        for (int j = 0; j < 4; j++) {
            long r = row0 + wr * 64 + m * 16 + quad * 4 + j;
            if (r < NNODES) {
                u16* op = out + r * HC + col0 + wc * 64 + l15;
                #pragma unroll
                for (int n = 0; n < 4; n++) op[n * 16] = f2b(acc[m][n][j]);
            }
        }
    }
}

// ---------------- a_s/a_d projection, vectorized uint2 loads ----------------
// K=64: 4 nodes per wave (16-lane groups), K=256: 1 node per wave. 8 B/lane coalesced.
template <int K, bool BN>
__global__ __launch_bounds__(256) void proj_att(const u16* __restrict__ X,
                                                const float* __restrict__ coef,
                                                const float* __restrict__ us,
                                                const float* __restrict__ ud,
                                                float* __restrict__ as_, float* __restrict__ ad_) {
    int gw = (blockIdx.x * 256 + threadIdx.x) >> 6;
    int lane = threadIdx.x & 63;
    int node, f0;
    if (K == 64) {
        node = gw * 4 + (lane >> 4);
        f0 = (lane & 15) * 4;
    } else {
        node = gw;
        f0 = lane * 4;
    }
    if (node >= NNODES) return;
    uint2 v = *(const uint2*)(X + (long)node * K + f0);
    float xv[4] = {b2f((u16)(v.x & 0xffffu)), b2f((u16)(v.x >> 16)),
                   b2f((u16)(v.y & 0xffffu)), b2f((u16)(v.y >> 16))};
    float pas[4] = {0.f, 0.f, 0.f, 0.f}, pad[4] = {0.f, 0.f, 0.f, 0.f};
    #pragma unroll
    for (int j = 0; j < 4; j++) {
        int f = f0 + j;
        float x = xv[j];
        if (BN) x = fmaxf(x * coef[f] + coef[256 + f], 0.f);
        #pragma unroll
        for (int h = 0; h < 4; h++) {
            pas[h] += x * us[f * 4 + h];
            pad[h] += x * ud[f * 4 + h];
        }
    }
    const int omax = (K == 64) ? 8 : 32;
    #pragma unroll
    for (int h = 0; h < 4; h++) {
        for (int o = omax; o; o >>= 1) {
            pas[h] += __shfl_xor(pas[h], o);
            pad[h] += __shfl_xor(pad[h], o);
        }
    }
    bool wr = (K == 64) ? ((lane & 15) == 0) : (lane == 0);
    if (wr) {
        #pragma unroll
        for (int h = 0; h < 4; h++) {
            as_[node * 4 + h] = pas[h];
            ad_[node * 4 + h] = pad[h];
        }
    }
}

// ---------------- fused GAT attention, one wave per dst node ----------------
__global__ __launch_bounds__(256) void gat_fused(
    const u16* __restrict__ xs, const float* __restrict__ as_, const float* __restrict__ ad_,
    const uint4* __restrict__ rec, int layer,
    const int* __restrict__ off, const int* __restrict__ deg,
    const u16* __restrict__ bias, u16* __restrict__ out) {
    __shared__ int s_lds[4][64];
    __shared__ float w_lds[4][64][4];
    int wid = (blockIdx.x * 256 + threadIdx.x) >> 6;
    if (wid >= NNODES) return;
    int wave = threadIdx.x >> 6;
    int lane = threadIdx.x & 63;
    int d = wid;
    int st = off[d], dg = deg[d];
    int slot = lane >> 2, h = lane & 3;
    float adv = ad_[d * 4 + h];
    float m = -1e30f, s = 0.f, sae = 0.f;
    const uint4* rbase = rec + (long)st * 2 + layer;

    if (dg <= 64) {
        // ---- phase 1 ----
        for (int i = slot; i < dg; i += 16) {
            uint4 r4 = rbase[(long)i * 2];
            int src = (int)r4.x;
            unsigned wsel = (h & 2) ? r4.z : r4.y;
            float aev = b2f((u16)((h & 1) ? (wsel >> 16) : (wsel & 0xffffu)));
            float t = as_[src * 4 + h] + adv + aev;
            float lg = (t > 0.f) ? t : 0.2f * t;
            if (h == 0) s_lds[wave][i] = src;
            w_lds[wave][i][h] = lg;
            sae += aev;
            float mn = fmaxf(m, lg);
            s = s * __expf(m - mn) + __expf(lg - mn);
            m = mn;
        }
        #pragma unroll
        for (int o = 4; o < 64; o <<= 1) {
            float mo = __shfl_xor(m, o), so = __shfl_xor(s, o), ao = __shfl_xor(sae, o);
            float mn = fmaxf(m, mo);
            s = s * __expf(m - mn) + so * __expf(mo - mn);
            m = mn;
            sae += ao;
        }
        float invs, wself;
        {
            float asv = as_[d * 4 + h];
            float l0 = asv + adv + sae / fmaxf((float)dg, 1.f);
            l0 = (l0 > 0.f) ? l0 : 0.2f * l0;
            float mn = fmaxf(m, l0);
            s = s * __expf(m - mn) + __expf(l0 - mn);
            m = mn;
            invs = 1.f / s;
            wself = __expf(l0 - mn) * invs;
        }
        for (int i = slot; i < dg; i += 16)
            w_lds[wave][i][h] = __expf(w_lds[wave][i][h] - m) * invs;

        // ---- phase 2: 32 lanes x uint4 cover the row; 8 edges in flight per wave ----
        int cg = lane & 31, half = lane >> 5;
        int ch8 = cg * 8;
        int h2 = cg >> 3;
        float ws2 = __shfl(wself, h2);
        const u16* xbase = xs + ch8;
        float a0, a1, a2, a3, a4, a5, a6, a7;
        {
            uint4 v = *(const uint4*)(xbase + (long)d * HC);
            float wsf = half ? 0.f : ws2;
            a0 = wsf * b2f((u16)(v.x & 0xffffu)); a1 = wsf * b2f((u16)(v.x >> 16));
            a2 = wsf * b2f((u16)(v.y & 0xffffu)); a3 = wsf * b2f((u16)(v.y >> 16));
            a4 = wsf * b2f((u16)(v.z & 0xffffu)); a5 = wsf * b2f((u16)(v.z >> 16));
            a6 = wsf * b2f((u16)(v.w & 0xffffu)); a7 = wsf * b2f((u16)(v.w >> 16));
        }
        int i = half;
        for (; i + 6 < dg; i += 8) {
            float wA = w_lds[wave][i][h2];     int sA = s_lds[wave][i];
            float wB = w_lds[wave][i + 2][h2]; int sB = s_lds[wave][i + 2];
            float wC = w_lds[wave][i + 4][h2]; int sC = s_lds[wave][i + 4];
            float wD = w_lds[wave][i + 6][h2]; int sD = s_lds[wave][i + 6];
            uint4 vA = *(const uint4*)(xbase + (long)sA * HC);
            uint4 vB = *(const uint4*)(xbase + (long)sB * HC);
            uint4 vC = *(const uint4*)(xbase + (long)sC * HC);
            uint4 vD = *(const uint4*)(xbase + (long)sD * HC);
            a0 += wA * b2f((u16)(vA.x & 0xffffu)) + wB * b2f((u16)(vB.x & 0xffffu))
                + wC * b2f((u16)(vC.x & 0xffffu)) + wD * b2f((u16)(vD.x & 0xffffu));
            a1 += wA * b2f((u16)(vA.x >> 16))     + wB * b2f((u16)(vB.x >> 16))
                + wC * b2f((u16)(vC.x >> 16))     + wD * b2f((u16)(vD.x >> 16));
            a2 += wA * b2f((u16)(vA.y & 0xffffu)) + wB * b2f((u16)(vB.y & 0xffffu))
                + wC * b2f((u16)(vC.y & 0xffffu)) + wD * b2f((u16)(vD.y & 0xffffu));
            a3 += wA * b2f((u16)(vA.y >> 16))     + wB * b2f((u16)(vB.y >> 16))
                + wC * b2f((u16)(vC.y >> 16))     + wD * b2f((u16)(vD.y >> 16));
            a4 += wA * b2f((u16)(vA.z & 0xffffu)) + wB * b2f((u16)(vB.z & 0xffffu))
                + wC * b2f((u16)(vC.z & 0xffffu)) + wD * b2f((u16)(vD.z & 0xffffu));
            a5 += wA * b2f((u16)(vA.z >> 16))     + wB * b2f((u16)(vB.z >> 16))
                + wC * b2f((u16)(vC.z >> 16))     + wD * b2f((u16)(vD.z >> 16));
            a6 += wA * b2f((u16)(vA.w & 0xffffu)) + wB * b2f((u16)(vB.w & 0xffffu))
                + wC * b2f((u16)(vC.w & 0xffffu)) + wD * b2f((u16)(vD.w & 0xffffu));
            a7 += wA * b2f((u16)(vA.w >> 16))     + wB * b2f((u16)(vB.w >> 16))
                + wC * b2f((u16)(vC.w >> 16))     + wD * b2f((u16)(vD.w >> 16));
        }
        for (; i < dg; i += 2) {
            float wA = w_lds[wave][i][h2]; int sA = s_lds[wave][i];
            uint4 vA = *(const uint4*)(xbase + (long)sA * HC);
            a0 += wA * b2f((u16)(vA.x & 0xffffu)); a1 += wA * b2f((u16)(vA.x >> 16));
            a2 += wA * b2f((u16)(vA.y & 0xffffu)); a3 += wA * b2f((u16)(vA.y >> 16));
            a4 += wA * b2f((u16)(vA.z & 0xffffu)); a5 += wA * b2f((u16)(vA.z >> 16));
            a6 += wA * b2f((u16)(vA.w & 0xffffu)); a7 += wA * b2f((u16)(vA.w >> 16));
        }
        a0 += __shfl_xor(a0, 32); a1 += __shfl_xor(a1, 32);
        a2 += __shfl_xor(a2, 32); a3 += __shfl_xor(a3, 32);
        a4 += __shfl_xor(a4, 32); a5 += __shfl_xor(a5, 32);
        a6 += __shfl_xor(a6, 32); a7 += __shfl_xor(a7, 32);
        if (half == 0) {
            uint4 bv = *(const uint4*)(bias + ch8);
            a0 += b2f((u16)(bv.x & 0xffffu)); a1 += b2f((u16)(bv.x >> 16));
            a2 += b2f((u16)(bv.y & 0xffffu)); a3 += b2f((u16)(bv.y >> 16));
            a4 += b2f((u16)(bv.z & 0xffffu)); a5 += b2f((u16)(bv.z >> 16));
            a6 += b2f((u16)(bv.w & 0xffffu)); a7 += b2f((u16)(bv.w >> 16));
            uint4 ov;
            ov.x = (unsigned)f2b(a0) | ((unsigned)f2b(a1) << 16);
            ov.y = (unsigned)f2b(a2) | ((unsigned)f2b(a3) << 16);
            ov.z = (unsigned)f2b(a4) | ((unsigned)f2b(a5) << 16);
            ov.w = (unsigned)f2b(a6) | ((unsigned)f2b(a7) << 16);
            *(uint4*)(out + (long)d * HC + ch8) = ov;
        }
        return;
    }

    // ---------- fallback path (deg > 64): exact ----------
    for (int base = 0; base < dg; base += 16) {
        int i = base + slot;
        float lg = -1e30f, aev = 0.f, w = 0.f;
        if (i < dg) {
            uint4 r4 = rbase[(long)i * 2];
            int src = (int)r4.x;
            unsigned wsel = (h & 2) ? r4.z : r4.y;
            aev = b2f((u16)((h & 1) ? (wsel >> 16) : (wsel & 0xffffu)));
            float t = as_[src * 4 + h] + adv + aev;
            lg = (t > 0.f) ? t : 0.2f * t;
        }
        sae += aev;
        float mn = fmaxf(m, lg);
        if (i < dg) w = __expf(lg - mn);
        s = s * __expf(m - mn) + w;
        m = mn;
    }
    #pragma unroll
    for (int o = 4; o < 64; o <<= 1) {
        float mo = __shfl_xor(m, o), so = __shfl_xor(s, o), ao = __shfl_xor(sae, o);
        float mn = fmaxf(m, mo);
        s = s * __expf(m - mn) + so * __expf(mo - mn);
        m = mn;
        sae += ao;
    }
    float invs, wself;
    {
        float asv = as_[d * 4 + h];
        float l0 = asv + adv + sae / fmaxf((float)dg, 1.f);
        l0 = (l0 > 0.f) ? l0 : 0.2f * l0;
        float mn = fmaxf(m, l0);
        s = s * __expf(m - mn) + __expf(l0 - mn);
        m = mn;
        invs = 1.f / s;
        wself = __expf(l0 - mn) * invs;
    }
    int h2 = lane >> 4;
    float m2 = __shfl(m, h2);
    float is2 = __shfl(invs, h2);
    float ws2 = __shfl(wself, h2);
    float adv2 = __shfl(adv, h2);
    int cb = lane * 4;
    float a0, a1, a2, a3;
    {
        uint2 v = *(const uint2*)(xs + (long)d * HC + cb);
        a0 = ws2 * b2f((u16)(v.x & 0xffffu)); a1 = ws2 * b2f((u16)(v.x >> 16));
        a2 = ws2 * b2f((u16)(v.y & 0xffffu)); a3 = ws2 * b2f((u16)(v.y >> 16));
    }
    int slot16 = lane & 15;
    int lhi = lane & 48;
    for (int base = 0; base < dg; base += 16) {
        int cnt = min(16, dg - base);
        float wv = 0.f;
        int srcl = 0;
        if (slot16 < cnt) {
            uint4 r4 = rbase[(long)(base + slot16) * 2];
            srcl = (int)r4.x;
            unsigned wsel = (h2 & 2) ? r4.z : r4.y;
            float aev = b2f((u16)((h2 & 1) ? (wsel >> 16) : (wsel & 0xffffu)));
            float t = as_[srcl * 4 + h2] + adv2 + aev;
            t = (t > 0.f) ? t : 0.2f * t;
            wv = __expf(t - m2) * is2;
        }
        for (int j = 0; j < cnt; j++) {
            float w0 = __shfl(wv, lhi | j);
            int s0 = __shfl(srcl, j);
            uint2 v0 = *(const uint2*)(xs + (long)s0 * HC + cb);
            a0 += w0 * b2f((u16)(v0.x & 0xffffu));
            a1 += w0 * b2f((u16)(v0.x >> 16));
            a2 += w0 * b2f((u16)(v0.y & 0xffffu));
            a3 += w0 * b2f((u16)(v0.y >> 16));
        }
    }
    u16 o0 = f2b(a0 + b2f(bias[cb + 0]));
    u16 o1 = f2b(a1 + b2f(bias[cb + 1]));
    u16 o2 = f2b(a2 + b2f(bias[cb + 2]));
    u16 o3 = f2b(a3 + b2f(bias[cb + 3]));
    uint2 ov;
    ov.x = (unsigned)o0 | ((unsigned)o1 << 16);
    ov.y = (unsigned)o2 | ((unsigned)o3 << 16);
    *(uint2*)(out + (long)d * HC + cb) = ov;
}

// ---------------- BatchNorm stats ----------------
__global__ void bn_stats(const u16* __restrict__ h, float* __restrict__ stats) {
    int c = threadIdx.x;
    float s = 0.f, q = 0.f;
    for (int r = blockIdx.x; r < NNODES; r += gridDim.x) {
        float v = b2f(h[(long)r * HC + c]);
        s += v;
        q += v * v;
    }
    atomicAdd(&stats[c], s);
    atomicAdd(&stats[256 + c], q);
}

// ---------------- output head (+fused BN2+ReLU) ----------------
__global__ __launch_bounds__(256) void out_head(const u16* __restrict__ h,
                                                const float* __restrict__ coef,
                                                const u16* __restrict__ wout,
                                                const u16* __restrict__ bout,
                                                void* __restrict__ y,
                                                const int* __restrict__ flag) {
    int wid = (blockIdx.x * 256 + threadIdx.x) >> 6;
    int lane = threadIdx.x & 63;
    if (wid >= NNODES) return;
    const u16* r = h + (long)wid * HC + lane * 4;
    int c0 = lane * 4;
    float p = 0.f;
    #pragma unroll
    for (int j = 0; j < 4; j++) {
        float v = b2f(r[j]);
        v = fmaxf(v * coef[c0 + j] + coef[256 + c0 + j], 0.f);
        p += v * b2f(wout[c0 + j]);
    }
    for (int o = 32; o; o >>= 1) p += __shfl_down(p, o);
    if (lane == 0) {
        float v = p + b2f(bout[0]);
        if (*flag) ((u16*)y)[wid] = f2b(v);
        else       ((float*)y)[wid] = v;
    }
}

extern "C" void kernel_launch(void* const* d_in, const int* in_sizes, int n_in,
                              void* d_out, int out_size, void* d_ws, size_t ws_size,
                              hipStream_t stream) {
    (void)in_sizes; (void)n_in; (void)out_size; (void)ws_size;
    const void* x_raw     = d_in[0];
    const int*  esrc      = (const int*)d_in[1];
    const int*  edst      = (const int*)d_in[2];
    const void* eattr_raw = d_in[3];

    char* ws = (char*)d_ws;
    size_t o = 0;
    auto alloc = [&](size_t bytes) -> char* {
        o = (o + 255) & ~(size_t)255;
        char* p = ws + o;
        o += bytes;
        return p;
    };
    int* dflag = (int*)alloc(256);
    u16* xb   = (u16*)alloc((size_t)NNODES * 64 * 2);
    u16* pall = (u16*)alloc((size_t)TOTP * 2);
    u16 *W1b = pall + hPO[0], *atts1b = pall + hPO[1], *attd1b = pall + hPO[2],
        *We1b = pall + hPO[3], *atte1b = pall + hPO[4], *b1b = pall + hPO[5],
        *g1b = pall + hPO[6], *be1b = pall + hPO[7], *W2b = pall + hPO[8],
        *atts2b = pall + hPO[9], *attd2b = pall + hPO[10], *We2b = pall + hPO[11],
        *atte2b = pall + hPO[12], *b2b = pall + hPO[13], *g2b = pall + hPO[14],
        *be2b = pall + hPO[15], *Woutb = pall + hPO[16], *boutb = pall + hPO[17];
    u16* WT1 = (u16*)alloc(256 * 64 * 2);
    u16* WT2 = (u16*)alloc(256 * 256 * 2);
    float* ve1 = (float*)alloc(64 * 4);
    float* ve2 = (float*)alloc(64 * 4);
    float* us1 = (float*)alloc(256 * 4);
    float* ud1 = (float*)alloc(256 * 4);
    float* us2 = (float*)alloc(1024 * 4);
    float* ud2 = (float*)alloc(1024 * 4);
    float* coef1 = (float*)alloc(512 * 4);
    float* coef2 = (float*)alloc(512 * 4);
    // zero zone: deg + stats
    int* deg = (int*)alloc((size_t)NNODES * 4);
    float* stats1 = (float*)alloc(512 * 4);
    float* stats2 = (float*)alloc(512 * 4);
    size_t zero_end = o;
    size_t zero_begin = (size_t)((char*)deg - ws);
    // rest
    int* off = (int*)alloc((size_t)NNODES * 4);
    int* cursor = (int*)alloc((size_t)NNODES * 4);
    int* bsums = (int*)alloc(256 * 4);
    int* boffs = (int*)alloc(256 * 4);
    uint4* rec = (uint4*)alloc((size_t)NEDGES * 32);
    float* as_ = (float*)alloc((size_t)NNODES * 16);
    float* ad_ = (float*)alloc((size_t)NNODES * 16);
    u16* bufA = (u16*)alloc((size_t)NNODES * HC * 2);  // xs1, then xs2
    u16* bufB = (u16*)alloc((size_t)NNODES * HC * 2);  // h1raw, then h2raw

    long zwords = (long)((zero_end - zero_begin) / 4);
    zero_init<<<128, 256, 0, stream>>>((unsigned*)(ws + zero_begin), zwords);
    detect_dtype<<<1, 256, 0, stream>>>((const unsigned*)x_raw, dflag);

    cvt_bf16<<<2048, 256, 0, stream>>>(x_raw, xb, NNODES * 64, dflag);
    Ptrs18 pp;
    for (int i = 0; i < 18; i++) pp.s[i] = d_in[4 + i];
    cvt_params<<<(TOTP + 255) / 256, 256, 0, stream>>>(pp, pall, dflag);

    transpose_w<<<64, 256, 0, stream>>>(W1b, WT1, 64);
    transpose_w<<<256, 256, 0, stream>>>(W2b, WT2, 256);
    proj_weight<<<1, 256, 0, stream>>>(We1b, atte1b, ve1, 16);
    proj_weight<<<1, 256, 0, stream>>>(We2b, atte2b, ve2, 16);
    proj_weight2<<<1, 256, 0, stream>>>(W1b, atts1b, attd1b, us1, ud1, 64);
    proj_weight2<<<4, 256, 0, stream>>>(W2b, atts2b, attd2b, us2, ud2, 256);

    int eblocks = (NEDGES + 255) / 256;
    int nb = (NNODES + 255) / 256;  // 196
    edge_deg<<<eblocks, 256, 0, stream>>>(edst, deg);
    block_sum<<<nb, 256, 0, stream>>>(deg, bsums, NNODES);
    scan_bsums<<<1, 256, 0, stream>>>(bsums, boffs, nb);
    write_offsets<<<nb, 256, 0, stream>>>(deg, boffs, off, cursor, NNODES);
    edge_stage<<<eblocks, 256, 0, stream>>>(eattr_raw, dflag, esrc, edst, ve1, ve2,
                                            cursor, rec);

    int gtiles = ((NNODES + 127) / 128) * 2;  // 782
    int wblocks = (NNODES * 64 + 255) / 256;  // 12500 (1 wave per node)
    int pblocks64 = (NNODES + 15) / 16;       // 3125 (4 nodes per wave)

    // layer 1 (xb: K=64)
    gemm_tile<64><<<gtiles, 256, 0, stream>>>(xb, WT1, bufA);
    proj_att<64, false><<<pblocks64, 256, 0, stream>>>(xb, nullptr, us1, ud1, as_, ad_);
    gat_fused<<<wblocks, 256, 0, stream>>>(bufA, as_, ad_, rec, 0, off, deg, b1b, bufB);
    bn_stats<<<512, 256, 0, stream>>>(bufB, stats1);
    bn_coef<<<1, 256, 0, stream>>>(stats1, g1b, be1b, coef1);

    // layer 2: materialize ReLU(BN1(h1)) in place, then plain GEMM + proj
    bn_apply<<<2048, 256, 0, stream>>>(bufB, coef1);
    gemm_tile<256><<<gtiles, 256, 0, stream>>>(bufB, WT2, bufA);
    proj_att<256, false><<<wblocks, 256, 0, stream>>>(bufB, nullptr, us2, ud2, as_, ad_);
    gat_fused<<<wblocks, 256, 0, stream>>>(bufA, as_, ad_, rec, 1, off, deg, b2b, bufB);
    bn_stats<<<512, 256, 0, stream>>>(bufB, stats2);
    bn_coef<<<1, 256, 0, stream>>>(stats2, g2b, be2b, coef2);

    // output head (BN2 fused)
    out_head<<<wblocks, 256, 0, stream>>>(bufB, coef2, Woutb, boutb, d_out, dflag);
}

// Round 5
// 542.302 us; speedup vs baseline: 1.4872x; 1.0081x over previous
//
#include <hip/hip_runtime.h>
#include <hip/hip_bf16.h>
#include <stdint.h>

#define NNODES 50000
#define NEDGES 800000
#define HC 256

typedef unsigned short u16;
typedef __attribute__((ext_vector_type(8))) short bf16x8;
typedef __attribute__((ext_vector_type(4))) float f32x4;

__device__ __forceinline__ float b2f(u16 v) {
    return __uint_as_float(((unsigned)v) << 16);
}
__device__ __forceinline__ u16 f2b(float f) {
    unsigned u = __float_as_uint(f);
    u += 0x7fff + ((u >> 16) & 1);
    return (u16)(u >> 16);
}

// param table: W1,atts1,attd1,We1,atte1,b1,g1,be1,W2,atts2,attd2,We2,atte2,b2,g2,be2,Wout,bout
__device__ __constant__ int dPO[19] = {0,16384,16640,16896,20992,21248,21504,21760,22016,
                                       87552,87808,88064,92160,92416,92672,92928,93184,93440,93441};
static const int hPO[19] = {0,16384,16640,16896,20992,21248,21504,21760,22016,
                            87552,87808,88064,92160,92416,92672,92928,93184,93440,93441};
#define TOTP 93441

__global__ void zero_init(unsigned* __restrict__ p, long nwords) {
    long i = (long)blockIdx.x * blockDim.x + threadIdx.x;
    long stride = (long)gridDim.x * blockDim.x;
    for (; i < nwords; i += stride) p[i] = 0u;
}

// 1 = bf16 inputs, 0 = fp32 inputs
__global__ void detect_dtype(const unsigned* __restrict__ xbits, int* __restrict__ flag) {
    __shared__ int cnt;
    if (threadIdx.x == 0) cnt = 0;
    __syncthreads();
    int sane = 0;
    for (int i = threadIdx.x; i < 1024; i += 256) {
        unsigned lo = xbits[i] & 0xffffu;
        int e = (int)((lo >> 7) & 0xff);
        if (e >= 117 && e <= 133) sane++;
    }
    atomicAdd(&cnt, sane);
    __syncthreads();
    if (threadIdx.x == 0) *flag = (cnt >= 512) ? 1 : 0;
}

// vectorized: n must be a multiple of 8 (octet-granular)
__global__ void cvt_bf16(const void* __restrict__ src, u16* __restrict__ dst, int n,
                         const int* __restrict__ flag) {
    int isbf16 = *flag;
    long no = (long)n >> 3;
    long i = (long)blockIdx.x * 256 + threadIdx.x;
    long stride = (long)gridDim.x * 256;
    if (isbf16) {
        const uint4* s = (const uint4*)src;
        uint4* d = (uint4*)dst;
        for (; i < no; i += stride) d[i] = s[i];
    } else {
        const float4* s = (const float4*)src;
        uint4* d = (uint4*)dst;
        for (; i < no; i += stride) {
            float4 a = s[i * 2], b = s[i * 2 + 1];
            uint4 o;
            o.x = (unsigned)f2b(a.x) | ((unsigned)f2b(a.y) << 16);
            o.y = (unsigned)f2b(a.z) | ((unsigned)f2b(a.w) << 16);
            o.z = (unsigned)f2b(b.x) | ((unsigned)f2b(b.y) << 16);
            o.w = (unsigned)f2b(b.z) | ((unsigned)f2b(b.w) << 16);
            d[i] = o;
        }
    }
}

struct Ptrs18 { const void* s[18]; };
__global__ void cvt_params(Ptrs18 p, u16* __restrict__ dst, const int* __restrict__ flag) {
    int i = blockIdx.x * 256 + threadIdx.x;
    if (i >= TOTP) return;
    int isbf16 = *flag;
    int idx = 0;
    #pragma unroll
    for (int j = 1; j < 18; j++) idx += (i >= dPO[j]) ? 1 : 0;
    int rel = i - dPO[idx];
    dst[i] = isbf16 ? ((const u16*)p.s[idx])[rel] : f2b(((const float*)p.s[idx])[rel]);
}

__global__ void proj_weight(const u16* __restrict__ W, const u16* __restrict__ att,
                            float* __restrict__ out, int R) {
    int i = blockIdx.x * 256 + threadIdx.x;
    if (i >= R * 4) return;
    int f = i >> 2, h = i & 3;
    float s = 0.f;
    for (int c = 0; c < 64; c++)
        s += b2f(W[f * 256 + h * 64 + c]) * b2f(att[h * 64 + c]);
    out[i] = s;
}

__global__ void proj_weight2(const u16* __restrict__ W, const u16* __restrict__ atta,
                             const u16* __restrict__ attb,
                             float* __restrict__ outa, float* __restrict__ outb, int R) {
    int i = blockIdx.x * 256 + threadIdx.x;
    if (i >= R * 4) return;
    int f = i >> 2, h = i & 3;
    float sa = 0.f, sb = 0.f;
    for (int c = 0; c < 64; c++) {
        float w = b2f(W[f * 256 + h * 64 + c]);
        sa += w * b2f(atta[h * 64 + c]);
        sb += w * b2f(attb[h * 64 + c]);
    }
    outa[i] = sa;
    outb[i] = sb;
}

// W[K][256] -> WT[256][K]
__global__ void transpose_w(const u16* __restrict__ W, u16* __restrict__ WT, int K) {
    int i = blockIdx.x * 256 + threadIdx.x;
    if (i >= K * 256) return;
    int k = i / 256, c = i % 256;
    WT[c * K + k] = W[i];
}

// ---------------- degree histogram ----------------
__global__ void edge_deg(const int* __restrict__ edst, int* __restrict__ deg) {
    int e = blockIdx.x * 256 + threadIdx.x;
    if (e >= NEDGES) return;
    atomicAdd(&deg[edst[e]], 1);
}

// ---------------- CSR scan ----------------
__global__ void block_sum(const int* __restrict__ deg, int* __restrict__ bsums, int n) {
    __shared__ int lds[256];
    int i = blockIdx.x * 256 + threadIdx.x;
    lds[threadIdx.x] = (i < n) ? deg[i] : 0;
    __syncthreads();
    for (int s = 128; s; s >>= 1) {
        if (threadIdx.x < s) lds[threadIdx.x] += lds[threadIdx.x + s];
        __syncthreads();
    }
    if (threadIdx.x == 0) bsums[blockIdx.x] = lds[0];
}

__global__ void scan_bsums(const int* __restrict__ bsums, int* __restrict__ boffs, int nb) {
    __shared__ int lds[256];
    int t = threadIdx.x;
    int v = (t < nb) ? bsums[t] : 0;
    lds[t] = v;
    __syncthreads();
    for (int s = 1; s < 256; s <<= 1) {
        int u = (t >= s) ? lds[t - s] : 0;
        __syncthreads();
        lds[t] += u;
        __syncthreads();
    }
    boffs[t] = lds[t] - v;  // exclusive
}

__global__ void write_offsets(const int* __restrict__ deg, const int* __restrict__ boffs,
                              int* __restrict__ off, int* __restrict__ cursor, int n) {
    __shared__ int lds[256];
    int t = threadIdx.x;
    int i = blockIdx.x * 256 + t;
    int v = (i < n) ? deg[i] : 0;
    lds[t] = v;
    __syncthreads();
    for (int s = 1; s < 256; s <<= 1) {
        int u = (t >= s) ? lds[t - s] : 0;
        __syncthreads();
        lds[t] += u;
        __syncthreads();
    }
    int exc = lds[t] - v + boffs[blockIdx.x];
    if (i < n) { off[i] = exc; cursor[i] = exc; }
}

// ---------------- edge stage: one 32B record per edge, scattered once ----------------
__global__ __launch_bounds__(256) void edge_stage(
    const void* __restrict__ eattr_raw, const int* __restrict__ flag,
    const int* __restrict__ esrc, const int* __restrict__ edst,
    const float* __restrict__ ve1, const float* __restrict__ ve2,
    int* __restrict__ cursor, uint4* __restrict__ rec) {
    int e = blockIdx.x * 256 + threadIdx.x;
    if (e >= NEDGES) return;
    float a[16];
    if (*flag) {
        const u16* s = (const u16*)eattr_raw + (long)e * 16;
        const uint4* q = (const uint4*)s;
        uint4 q0 = q[0], q1 = q[1];
        unsigned w0[8] = {q0.x, q0.y, q0.z, q0.w, q1.x, q1.y, q1.z, q1.w};
        #pragma unroll
        for (int j = 0; j < 8; j++) {
            a[2 * j] = b2f((u16)(w0[j] & 0xffff));
            a[2 * j + 1] = b2f((u16)(w0[j] >> 16));
        }
    } else {
        const float* s = (const float*)eattr_raw + (long)e * 16;
        #pragma unroll
        for (int j = 0; j < 16; j += 4) {
            float4 q = *(const float4*)(s + j);
            a[j] = q.x; a[j + 1] = q.y; a[j + 2] = q.z; a[j + 3] = q.w;
        }
    }
    float s1[4], s2[4];
    #pragma unroll
    for (int h = 0; h < 4; h++) {
        float t1 = 0.f, t2 = 0.f;
        #pragma unroll
        for (int f = 0; f < 16; f++) {
            t1 += a[f] * ve1[f * 4 + h];
            t2 += a[f] * ve2[f * 4 + h];
        }
        s1[h] = t1;
        s2[h] = t2;
    }
    unsigned a1lo = (unsigned)f2b(s1[0]) | ((unsigned)f2b(s1[1]) << 16);
    unsigned a1hi = (unsigned)f2b(s1[2]) | ((unsigned)f2b(s1[3]) << 16);
    unsigned a2lo = (unsigned)f2b(s2[0]) | ((unsigned)f2b(s2[1]) << 16);
    unsigned a2hi = (unsigned)f2b(s2[2]) | ((unsigned)f2b(s2[3]) << 16);
    int d = edst[e];
    int p = atomicAdd(&cursor[d], 1);
    unsigned src = (unsigned)esrc[e];
    rec[(long)p * 2 + 0] = make_uint4(src, a1lo, a1hi, 0u);
    rec[(long)p * 2 + 1] = make_uint4(src, a2lo, a2hi, 0u);
}

// ---------------- BN coefficient finalize: y = v*coef[c] + coef[256+c] ----------------
__global__ void bn_coef(const float* __restrict__ stats, const u16* __restrict__ g,
                        const u16* __restrict__ be, float* __restrict__ coef) {
    int c = threadIdx.x;  // 256
    float mu = stats[c] * (1.0f / NNODES);
    float var = stats[256 + c] * (1.0f / NNODES) - mu * mu;
    var = fmaxf(var, 0.f);
    float rs = rsqrtf(var + 1e-5f);
    float sc = b2f(g[c]) * rs;
    coef[c] = sc;
    coef[256 + c] = b2f(be[c]) - sc * mu;
}

// ---------------- tiled MFMA GEMM: C[M x 256] = A[M x K] * WT[256 x K]^T ----------------
// BN=true: apply y = relu(v*coef[k] + coef[256+k]) to A fragments in-register
// (identical rounding path to a materialized bn_apply: BN in f32 -> f2b -> MFMA).
__device__ __forceinline__ void gload_lds16(const u16* g, u16* l) {
    __builtin_amdgcn_global_load_lds(
        (const __attribute__((address_space(1))) unsigned*)g,
        (__attribute__((address_space(3))) unsigned*)l, 16, 0, 0);
}

template <int K, bool BN>
__global__ __launch_bounds__(256) void gemm_tile(const u16* __restrict__ A,
                                                 const u16* __restrict__ WT,
                                                 const float* __restrict__ coef,
                                                 u16* __restrict__ out) {
    __shared__ u16 As[128 * 32];  // [row][32] 64B rows
    __shared__ u16 Bs[128 * 32];
    int tid = threadIdx.x;
    int wave = tid >> 6, lane = tid & 63;
    int wr = wave >> 1, wc = wave & 1;
    int quad = lane >> 4, l15 = lane & 15;
    long row0 = (long)(blockIdx.x >> 1) * 128;
    int col0 = (blockIdx.x & 1) * 128;
    int srow = lane >> 2;        // 0..15: row within 16-row staging chunk
    int soct = (lane & 3) * 8;   // element offset within 32-elem row
    f32x4 acc[4][4] = {};
    for (int kk = 0; kk < K; kk += 32) {
        #pragma unroll
        for (int sub = 0; sub < 2; sub++) {
            int rr = wave * 32 + sub * 16;   // wave-uniform chunk base row
            long gr = row0 + rr + srow;
            if (gr >= NNODES) gr = NNODES - 1;  // clamp: read valid, store predicated
            gload_lds16(A + gr * K + kk + soct, &As[rr * 32]);
            gload_lds16(WT + (long)(col0 + rr + srow) * K + kk + soct, &Bs[rr * 32]);
        }
        __syncthreads();
        bf16x8 av[4], bv[4];
        #pragma unroll
        for (int m = 0; m < 4; m++)
            av[m] = *(const bf16x8*)&As[(wr * 64 + m * 16 + l15) * 32 + quad * 8];
        if (BN) {
            int kb = kk + quad * 8;
            float4 sc0 = *(const float4*)(coef + kb);
            float4 sc1 = *(const float4*)(coef + kb + 4);
            float4 sh0 = *(const float4*)(coef + 256 + kb);
            float4 sh1 = *(const float4*)(coef + 256 + kb + 4);
            float scl[8] = {sc0.x, sc0.y, sc0.z, sc0.w, sc1.x, sc1.y, sc1.z, sc1.w};
            float shf[8] = {sh0.x, sh0.y, sh0.z, sh0.w, sh1.x, sh1.y, sh1.z, sh1.w};
            #pragma unroll
            for (int m = 0; m < 4; m++) {
                #pragma unroll
                for (int j = 0; j < 8; j++) {
                    float v = b2f((u16)av[m][j]);
                    v = fmaxf(v * scl[j] + shf[j], 0.f);
                    av[m][j] = (short)f2b(v);
                }
            }
        }
        #pragma unroll
        for (int n = 0; n < 4; n++)
            bv[n] = *(const bf16x8*)&Bs[(wc * 64 + n * 16 + l15) * 32 + quad * 8];
        #pragma unroll
        for (int m = 0; m < 4; m++)
            #pragma unroll
            for (int n = 0; n < 4; n++)
                acc[m][n] = __builtin_amdgcn_mfma_f32_16x16x32_bf16(av[m], bv[n],
                                                                    acc[m][n], 0, 0, 0);
        __syncthreads();
    }
    #pragma unroll
    for (int m = 0; m < 4; m++) {
        #pragma unroll
        for (int j = 0; j < 4; j++) {
            long r = row0 + wr * 64 + m * 16 + quad * 4 + j;
            if (r < NNODES) {
                u16* op = out + r * HC + col0 + wc * 64 + l15;
                #pragma unroll
                for (int n = 0; n < 4; n++) op[n * 16] = f2b(acc[m][n][j]);
            }
        }
    }
}

// ---------------- a_s/a_d projection, vectorized uint2 loads ----------------
// K=64: 4 nodes per wave (16-lane groups), K=256: 1 node per wave. 8 B/lane coalesced.
template <int K, bool BN>
__global__ __launch_bounds__(256) void proj_att(const u16* __restrict__ X,
                                                const float* __restrict__ coef,
                                                const float* __restrict__ us,
                                                const float* __restrict__ ud,
                                                float* __restrict__ as_, float* __restrict__ ad_) {
    int gw = (blockIdx.x * 256 + threadIdx.x) >> 6;
    int lane = threadIdx.x & 63;
    int node, f0;
    if (K == 64) {
        node = gw * 4 + (lane >> 4);
        f0 = (lane & 15) * 4;
    } else {
        node = gw;
        f0 = lane * 4;
    }
    if (node >= NNODES) return;
    uint2 v = *(const uint2*)(X + (long)node * K + f0);
    float xv[4] = {b2f((u16)(v.x & 0xffffu)), b2f((u16)(v.x >> 16)),
                   b2f((u16)(v.y & 0xffffu)), b2f((u16)(v.y >> 16))};
    float pas[4] = {0.f, 0.f, 0.f, 0.f}, pad[4] = {0.f, 0.f, 0.f, 0.f};
    #pragma unroll
    for (int j = 0; j < 4; j++) {
        int f = f0 + j;
        float x = xv[j];
        if (BN) x = fmaxf(x * coef[f] + coef[256 + f], 0.f);
        #pragma unroll
        for (int h = 0; h < 4; h++) {
            pas[h] += x * us[f * 4 + h];
            pad[h] += x * ud[f * 4 + h];
        }
    }
    const int omax = (K == 64) ? 8 : 32;
    #pragma unroll
    for (int h = 0; h < 4; h++) {
        for (int o = omax; o; o >>= 1) {
            pas[h] += __shfl_xor(pas[h], o);
            pad[h] += __shfl_xor(pad[h], o);
        }
    }
    bool wr = (K == 64) ? ((lane & 15) == 0) : (lane == 0);
    if (wr) {
        #pragma unroll
        for (int h = 0; h < 4; h++) {
            as_[node * 4 + h] = pas[h];
            ad_[node * 4 + h] = pad[h];
        }
    }
}

// ---------------- fused GAT attention, one wave per dst node ----------------
__global__ __launch_bounds__(256) void gat_fused(
    const u16* __restrict__ xs, const float* __restrict__ as_, const float* __restrict__ ad_,
    const uint4* __restrict__ rec, int layer,
    const int* __restrict__ off, const int* __restrict__ deg,
    const u16* __restrict__ bias, u16* __restrict__ out) {
    __shared__ int s_lds[4][64];
    __shared__ float w_lds[4][64][4];
    int wid = (blockIdx.x * 256 + threadIdx.x) >> 6;
    if (wid >= NNODES) return;
    int wave = threadIdx.x >> 6;
    int lane = threadIdx.x & 63;
    int d = wid;
    int st = off[d], dg = deg[d];
    int slot = lane >> 2, h = lane & 3;
    float adv = ad_[d * 4 + h];
    float m = -1e30f, s = 0.f, sae = 0.f;
    const uint4* rbase = rec + (long)st * 2 + layer;

    if (dg <= 64) {
        // ---- phase 1 ----
        for (int i = slot; i < dg; i += 16) {
            uint4 r4 = rbase[(long)i * 2];
            int src = (int)r4.x;
            unsigned wsel = (h & 2) ? r4.z : r4.y;
            float aev = b2f((u16)((h & 1) ? (wsel >> 16) : (wsel & 0xffffu)));
            float t = as_[src * 4 + h] + adv + aev;
            float lg = (t > 0.f) ? t : 0.2f * t;
            if (h == 0) s_lds[wave][i] = src;
            w_lds[wave][i][h] = lg;
            sae += aev;
            float mn = fmaxf(m, lg);
            s = s * __expf(m - mn) + __expf(lg - mn);
            m = mn;
        }
        #pragma unroll
        for (int o = 4; o < 64; o <<= 1) {
            float mo = __shfl_xor(m, o), so = __shfl_xor(s, o), ao = __shfl_xor(sae, o);
            float mn = fmaxf(m, mo);
            s = s * __expf(m - mn) + so * __expf(mo - mn);
            m = mn;
            sae += ao;
        }
        float invs, wself;
        {
            float asv = as_[d * 4 + h];
            float l0 = asv + adv + sae / fmaxf((float)dg, 1.f);
            l0 = (l0 > 0.f) ? l0 : 0.2f * l0;
            float mn = fmaxf(m, l0);
            s = s * __expf(m - mn) + __expf(l0 - mn);
            m = mn;
            invs = 1.f / s;
            wself = __expf(l0 - mn) * invs;
        }
        for (int i = slot; i < dg; i += 16)
            w_lds[wave][i][h] = __expf(w_lds[wave][i][h] - m) * invs;

        // ---- phase 2: 32 lanes x uint4 cover the row; 8 edges in flight per wave ----
        int cg = lane & 31, half = lane >> 5;
        int ch8 = cg * 8;
        int h2 = cg >> 3;
        float ws2 = __shfl(wself, h2);
        const u16* xbase = xs + ch8;
        float a0, a1, a2, a3, a4, a5, a6, a7;
        {
            uint4 v = *(const uint4*)(xbase + (long)d * HC);
            float wsf = half ? 0.f : ws2;
            a0 = wsf * b2f((u16)(v.x & 0xffffu)); a1 = wsf * b2f((u16)(v.x >> 16));
            a2 = wsf * b2f((u16)(v.y & 0xffffu)); a3 = wsf * b2f((u16)(v.y >> 16));
            a4 = wsf * b2f((u16)(v.z & 0xffffu)); a5 = wsf * b2f((u16)(v.z >> 16));
            a6 = wsf * b2f((u16)(v.w & 0xffffu)); a7 = wsf * b2f((u16)(v.w >> 16));
        }
        int i = half;
        for (; i + 6 < dg; i += 8) {
            float wA = w_lds[wave][i][h2];     int sA = s_lds[wave][i];
            float wB = w_lds[wave][i + 2][h2]; int sB = s_lds[wave][i + 2];
            float wC = w_lds[wave][i + 4][h2]; int sC = s_lds[wave][i + 4];
            float wD = w_lds[wave][i + 6][h2]; int sD = s_lds[wave][i + 6];
            uint4 vA = *(const uint4*)(xbase + (long)sA * HC);
            uint4 vB = *(const uint4*)(xbase + (long)sB * HC);
            uint4 vC = *(const uint4*)(xbase + (long)sC * HC);
            uint4 vD = *(const uint4*)(xbase + (long)sD * HC);
            a0 += wA * b2f((u16)(vA.x & 0xffffu)) + wB * b2f((u16)(vB.x & 0xffffu))
                + wC * b2f((u16)(vC.x & 0xffffu)) + wD * b2f((u16)(vD.x & 0xffffu));
            a1 += wA * b2f((u16)(vA.x >> 16))     + wB * b2f((u16)(vB.x >> 16))
                + wC * b2f((u16)(vC.x >> 16))     + wD * b2f((u16)(vD.x >> 16));
            a2 += wA * b2f((u16)(vA.y & 0xffffu)) + wB * b2f((u16)(vB.y & 0xffffu))
                + wC * b2f((u16)(vC.y & 0xffffu)) + wD * b2f((u16)(vD.y & 0xffffu));
            a3 += wA * b2f((u16)(vA.y >> 16))     + wB * b2f((u16)(vB.y >> 16))
                + wC * b2f((u16)(vC.y >> 16))     + wD * b2f((u16)(vD.y >> 16));
            a4 += wA * b2f((u16)(vA.z & 0xffffu)) + wB * b2f((u16)(vB.z & 0xffffu))
                + wC * b2f((u16)(vC.z & 0xffffu)) + wD * b2f((u16)(vD.z & 0xffffu));
            a5 += wA * b2f((u16)(vA.z >> 16))     + wB * b2f((u16)(vB.z >> 16))
                + wC * b2f((u16)(vC.z >> 16))     + wD * b2f((u16)(vD.z >> 16));
            a6 += wA * b2f((u16)(vA.w & 0xffffu)) + wB * b2f((u16)(vB.w & 0xffffu))
                + wC * b2f((u16)(vC.w & 0xffffu)) + wD * b2f((u16)(vD.w & 0xffffu));
            a7 += wA * b2f((u16)(vA.w >> 16))     + wB * b2f((u16)(vB.w >> 16))
                + wC * b2f((u16)(vC.w >> 16))     + wD * b2f((u16)(vD.w >> 16));
        }
        for (; i < dg; i += 2) {
            float wA = w_lds[wave][i][h2]; int sA = s_lds[wave][i];
            uint4 vA = *(const uint4*)(xbase + (long)sA * HC);
            a0 += wA * b2f((u16)(vA.x & 0xffffu)); a1 += wA * b2f((u16)(vA.x >> 16));
            a2 += wA * b2f((u16)(vA.y & 0xffffu)); a3 += wA * b2f((u16)(vA.y >> 16));
            a4 += wA * b2f((u16)(vA.z & 0xffffu)); a5 += wA * b2f((u16)(vA.z >> 16));
            a6 += wA * b2f((u16)(vA.w & 0xffffu)); a7 += wA * b2f((u16)(vA.w >> 16));
        }
        a0 += __shfl_xor(a0, 32); a1 += __shfl_xor(a1, 32);
        a2 += __shfl_xor(a2, 32); a3 += __shfl_xor(a3, 32);
        a4 += __shfl_xor(a4, 32); a5 += __shfl_xor(a5, 32);
        a6 += __shfl_xor(a6, 32); a7 += __shfl_xor(a7, 32);
        if (half == 0) {
            uint4 bv = *(const uint4*)(bias + ch8);
            a0 += b2f((u16)(bv.x & 0xffffu)); a1 += b2f((u16)(bv.x >> 16));
            a2 += b2f((u16)(bv.y & 0xffffu)); a3 += b2f((u16)(bv.y >> 16));
            a4 += b2f((u16)(bv.z & 0xffffu)); a5 += b2f((u16)(bv.z >> 16));
            a6 += b2f((u16)(bv.w & 0xffffu)); a7 += b2f((u16)(bv.w >> 16));
            uint4 ov;
            ov.x = (unsigned)f2b(a0) | ((unsigned)f2b(a1) << 16);
            ov.y = (unsigned)f2b(a2) | ((unsigned)f2b(a3) << 16);
            ov.z = (unsigned)f2b(a4) | ((unsigned)f2b(a5) << 16);
            ov.w = (unsigned)f2b(a6) | ((unsigned)f2b(a7) << 16);
            *(uint4*)(out + (long)d * HC + ch8) = ov;
        }
        return;
    }

    // ---------- fallback path (deg > 64): exact ----------
    for (int base = 0; base < dg; base += 16) {
        int i = base + slot;
        float lg = -1e30f, aev = 0.f, w = 0.f;
        if (i < dg) {
            uint4 r4 = rbase[(long)i * 2];
            int src = (int)r4.x;
            unsigned wsel = (h & 2) ? r4.z : r4.y;
            aev = b2f((u16)((h & 1) ? (wsel >> 16) : (wsel & 0xffffu)));
            float t = as_[src * 4 + h] + adv + aev;
            lg = (t > 0.f) ? t : 0.2f * t;
        }
        sae += aev;
        float mn = fmaxf(m, lg);
        if (i < dg) w = __expf(lg - mn);
        s = s * __expf(m - mn) + w;
        m = mn;
    }
    #pragma unroll
    for (int o = 4; o < 64; o <<= 1) {
        float mo = __shfl_xor(m, o), so = __shfl_xor(s, o), ao = __shfl_xor(sae, o);
        float mn = fmaxf(m, mo);
        s = s * __expf(m - mn) + so * __expf(mo - mn);
        m = mn;
        sae += ao;
    }
    float invs, wself;
    {
        float asv = as_[d * 4 + h];
        float l0 = asv + adv + sae / fmaxf((float)dg, 1.f);
        l0 = (l0 > 0.f) ? l0 : 0.2f * l0;
        float mn = fmaxf(m, l0);
        s = s * __expf(m - mn) + __expf(l0 - mn);
        m = mn;
        invs = 1.f / s;
        wself = __expf(l0 - mn) * invs;
    }
    int h2 = lane >> 4;
    float m2 = __shfl(m, h2);
    float is2 = __shfl(invs, h2);
    float ws2 = __shfl(wself, h2);
    float adv2 = __shfl(adv, h2);
    int cb = lane * 4;
    float a0, a1, a2, a3;
    {
        uint2 v = *(const uint2*)(xs + (long)d * HC + cb);
        a0 = ws2 * b2f((u16)(v.x & 0xffffu)); a1 = ws2 * b2f((u16)(v.x >> 16));
        a2 = ws2 * b2f((u16)(v.y & 0xffffu)); a3 = ws2 * b2f((u16)(v.y >> 16));
    }
    int slot16 = lane & 15;
    int lhi = lane & 48;
    for (int base = 0; base < dg; base += 16) {
        int cnt = min(16, dg - base);
        float wv = 0.f;
        int srcl = 0;
        if (slot16 < cnt) {
            uint4 r4 = rbase[(long)(base + slot16) * 2];
            srcl = (int)r4.x;
            unsigned wsel = (h2 & 2) ? r4.z : r4.y;
            float aev = b2f((u16)((h2 & 1) ? (wsel >> 16) : (wsel & 0xffffu)));
            float t = as_[srcl * 4 + h2] + adv2 + aev;
            t = (t > 0.f) ? t : 0.2f * t;
            wv = __expf(t - m2) * is2;
        }
        for (int j = 0; j < cnt; j++) {
            float w0 = __shfl(wv, lhi | j);
            int s0 = __shfl(srcl, j);
            uint2 v0 = *(const uint2*)(xs + (long)s0 * HC + cb);
            a0 += w0 * b2f((u16)(v0.x & 0xffffu));
            a1 += w0 * b2f((u16)(v0.x >> 16));
            a2 += w0 * b2f((u16)(v0.y & 0xffffu));
            a3 += w0 * b2f((u16)(v0.y >> 16));
        }
    }
    u16 o0 = f2b(a0 + b2f(bias[cb + 0]));
    u16 o1 = f2b(a1 + b2f(bias[cb + 1]));
    u16 o2 = f2b(a2 + b2f(bias[cb + 2]));
    u16 o3 = f2b(a3 + b2f(bias[cb + 3]));
    uint2 ov;
    ov.x = (unsigned)o0 | ((unsigned)o1 << 16);
    ov.y = (unsigned)o2 | ((unsigned)o3 << 16);
    *(uint2*)(out + (long)d * HC + cb) = ov;
}

// ---------------- BatchNorm stats (vectorized 4B/lane + LDS pair-combine) ----------------
__global__ __launch_bounds__(256) void bn_stats(const u16* __restrict__ h,
                                                float* __restrict__ stats) {
    __shared__ float lsum[256], lsq[256];
    int t = threadIdx.x;
    int p = t & 127;   // col pair p -> cols 2p, 2p+1
    int ro = t >> 7;   // row phase 0/1
    float s0 = 0.f, q0 = 0.f, s1 = 0.f, q1 = 0.f;
    for (int r = blockIdx.x * 2 + ro; r < NNODES; r += gridDim.x * 2) {
        unsigned v = *(const unsigned*)(h + (long)r * HC + 2 * p);
        float lo = b2f((u16)(v & 0xffffu)), hi = b2f((u16)(v >> 16));
        s0 += lo; q0 += lo * lo;
        s1 += hi; q1 += hi * hi;
    }
    if (ro == 1) {
        lsum[2 * p] = s0; lsum[2 * p + 1] = s1;
        lsq[2 * p] = q0;  lsq[2 * p + 1] = q1;
    }
    __syncthreads();
    if (ro == 0) {
        atomicAdd(&stats[2 * p],           s0 + lsum[2 * p]);
        atomicAdd(&stats[2 * p + 1],       s1 + lsum[2 * p + 1]);
        atomicAdd(&stats[256 + 2 * p],     q0 + lsq[2 * p]);
        atomicAdd(&stats[256 + 2 * p + 1], q1 + lsq[2 * p + 1]);
    }
}

// ---------------- output head (+fused BN2+ReLU), vectorized ----------------
__global__ __launch_bounds__(256) void out_head(const u16* __restrict__ h,
                                                const float* __restrict__ coef,
                                                const u16* __restrict__ wout,
                                                const u16* __restrict__ bout,
                                                void* __restrict__ y,
                                                const int* __restrict__ flag) {
    int wid = (blockIdx.x * 256 + threadIdx.x) >> 6;
    int lane = threadIdx.x & 63;
    if (wid >= NNODES) return;
    int c0 = lane * 4;
    uint2 v = *(const uint2*)(h + (long)wid * HC + c0);
    uint2 wv = *(const uint2*)(wout + c0);
    float hv[4] = {b2f((u16)(v.x & 0xffffu)), b2f((u16)(v.x >> 16)),
                   b2f((u16)(v.y & 0xffffu)), b2f((u16)(v.y >> 16))};
    float wf[4] = {b2f((u16)(wv.x & 0xffffu)), b2f((u16)(wv.x >> 16)),
                   b2f((u16)(wv.y & 0xffffu)), b2f((u16)(wv.y >> 16))};
    float p = 0.f;
    #pragma unroll
    for (int j = 0; j < 4; j++) {
        float t = fmaxf(hv[j] * coef[c0 + j] + coef[256 + c0 + j], 0.f);
        p += t * wf[j];
    }
    for (int o = 32; o; o >>= 1) p += __shfl_down(p, o);
    if (lane == 0) {
        float t = p + b2f(bout[0]);
        if (*flag) ((u16*)y)[wid] = f2b(t);
        else       ((float*)y)[wid] = t;
    }
}

extern "C" void kernel_launch(void* const* d_in, const int* in_sizes, int n_in,
                              void* d_out, int out_size, void* d_ws, size_t ws_size,
                              hipStream_t stream) {
    (void)in_sizes; (void)n_in; (void)out_size; (void)ws_size;
    const void* x_raw     = d_in[0];
    const int*  esrc      = (const int*)d_in[1];
    const int*  edst      = (const int*)d_in[2];
    const void* eattr_raw = d_in[3];

    char* ws = (char*)d_ws;
    size_t o = 0;
    auto alloc = [&](size_t bytes) -> char* {
        o = (o + 255) & ~(size_t)255;
        char* p = ws + o;
        o += bytes;
        return p;
    };
    int* dflag = (int*)alloc(256);
    u16* xb   = (u16*)alloc((size_t)NNODES * 64 * 2);
    u16* pall = (u16*)alloc((size_t)TOTP * 2);
    u16 *W1b = pall + hPO[0], *atts1b = pall + hPO[1], *attd1b = pall + hPO[2],
        *We1b = pall + hPO[3], *atte1b = pall + hPO[4], *b1b = pall + hPO[5],
        *g1b = pall + hPO[6], *be1b = pall + hPO[7], *W2b = pall + hPO[8],
        *atts2b = pall + hPO[9], *attd2b = pall + hPO[10], *We2b = pall + hPO[11],
        *atte2b = pall + hPO[12], *b2b = pall + hPO[13], *g2b = pall + hPO[14],
        *be2b = pall + hPO[15], *Woutb = pall + hPO[16], *boutb = pall + hPO[17];
    u16* WT1 = (u16*)alloc(256 * 64 * 2);
    u16* WT2 = (u16*)alloc(256 * 256 * 2);
    float* ve1 = (float*)alloc(64 * 4);
    float* ve2 = (float*)alloc(64 * 4);
    float* us1 = (float*)alloc(256 * 4);
    float* ud1 = (float*)alloc(256 * 4);
    float* us2 = (float*)alloc(1024 * 4);
    float* ud2 = (float*)alloc(1024 * 4);
    float* coef1 = (float*)alloc(512 * 4);
    float* coef2 = (float*)alloc(512 * 4);
    // zero zone: deg + stats
    int* deg = (int*)alloc((size_t)NNODES * 4);
    float* stats1 = (float*)alloc(512 * 4);
    float* stats2 = (float*)alloc(512 * 4);
    size_t zero_end = o;
    size_t zero_begin = (size_t)((char*)deg - ws);
    // rest
    int* off = (int*)alloc((size_t)NNODES * 4);
    int* cursor = (int*)alloc((size_t)NNODES * 4);
    int* bsums = (int*)alloc(256 * 4);
    int* boffs = (int*)alloc(256 * 4);
    uint4* rec = (uint4*)alloc((size_t)NEDGES * 32);
    float* as_ = (float*)alloc((size_t)NNODES * 16);
    float* ad_ = (float*)alloc((size_t)NNODES * 16);
    u16* bufA = (u16*)alloc((size_t)NNODES * HC * 2);  // xs1, then xs2
    u16* bufB = (u16*)alloc((size_t)NNODES * HC * 2);  // h1raw, then h2raw

    long zwords = (long)((zero_end - zero_begin) / 4);
    zero_init<<<128, 256, 0, stream>>>((unsigned*)(ws + zero_begin), zwords);
    detect_dtype<<<1, 256, 0, stream>>>((const unsigned*)x_raw, dflag);

    cvt_bf16<<<1024, 256, 0, stream>>>(x_raw, xb, NNODES * 64, dflag);
    Ptrs18 pp;
    for (int i = 0; i < 18; i++) pp.s[i] = d_in[4 + i];
    cvt_params<<<(TOTP + 255) / 256, 256, 0, stream>>>(pp, pall, dflag);

    transpose_w<<<64, 256, 0, stream>>>(W1b, WT1, 64);
    transpose_w<<<256, 256, 0, stream>>>(W2b, WT2, 256);
    proj_weight<<<1, 256, 0, stream>>>(We1b, atte1b, ve1, 16);
    proj_weight<<<1, 256, 0, stream>>>(We2b, atte2b, ve2, 16);
    proj_weight2<<<1, 256, 0, stream>>>(W1b, atts1b, attd1b, us1, ud1, 64);
    proj_weight2<<<4, 256, 0, stream>>>(W2b, atts2b, attd2b, us2, ud2, 256);

    int eblocks = (NEDGES + 255) / 256;
    int nb = (NNODES + 255) / 256;  // 196
    edge_deg<<<eblocks, 256, 0, stream>>>(edst, deg);
    block_sum<<<nb, 256, 0, stream>>>(deg, bsums, NNODES);
    scan_bsums<<<1, 256, 0, stream>>>(bsums, boffs, nb);
    write_offsets<<<nb, 256, 0, stream>>>(deg, boffs, off, cursor, NNODES);
    edge_stage<<<eblocks, 256, 0, stream>>>(eattr_raw, dflag, esrc, edst, ve1, ve2,
                                            cursor, rec);

    int gtiles = ((NNODES + 127) / 128) * 2;  // 782
    int wblocks = (NNODES * 64 + 255) / 256;  // 12500 (1 wave per node)
    int pblocks64 = (NNODES + 15) / 16;       // 3125 (4 nodes per wave)

    // layer 1 (xb: K=64)
    gemm_tile<64, false><<<gtiles, 256, 0, stream>>>(xb, WT1, nullptr, bufA);
    proj_att<64, false><<<pblocks64, 256, 0, stream>>>(xb, nullptr, us1, ud1, as_, ad_);
    gat_fused<<<wblocks, 256, 0, stream>>>(bufA, as_, ad_, rec, 0, off, deg, b1b, bufB);
    bn_stats<<<256, 256, 0, stream>>>(bufB, stats1);
    bn_coef<<<1, 256, 0, stream>>>(stats1, g1b, be1b, coef1);

    // layer 2: BN1 fused into GEMM A-path and proj_att (no bn_apply materialization)
    gemm_tile<256, true><<<gtiles, 256, 0, stream>>>(bufB, WT2, coef1, bufA);
    proj_att<256, true><<<wblocks, 256, 0, stream>>>(bufB, coef1, us2, ud2, as_, ad_);
    gat_fused<<<wblocks, 256, 0, stream>>>(bufA, as_, ad_, rec, 1, off, deg, b2b, bufB);
    bn_stats<<<256, 256, 0, stream>>>(bufB, stats2);
    bn_coef<<<1, 256, 0, stream>>>(stats2, g2b, be2b, coef2);

    // output head (BN2 fused)
    out_head<<<wblocks, 256, 0, stream>>>(bufB, coef2, Woutb, boutb, d_out, dflag);
}

// Round 7
// 538.866 us; speedup vs baseline: 1.4967x; 1.0064x over previous
//
#include <hip/hip_runtime.h>
#include <hip/hip_bf16.h>
#include <stdint.h>

#define NNODES 50000
#define NEDGES 800000
#define HC 256

typedef unsigned short u16;
typedef __attribute__((ext_vector_type(8))) short bf16x8;
typedef __attribute__((ext_vector_type(4))) float f32x4;

__device__ __forceinline__ float b2f(u16 v) {
    return __uint_as_float(((unsigned)v) << 16);
}
__device__ __forceinline__ u16 f2b(float f) {
    unsigned u = __float_as_uint(f);
    u += 0x7fff + ((u >> 16) & 1);
    return (u16)(u >> 16);
}
__device__ __forceinline__ float rdp(const void* p, long i, int bf) {
    return bf ? b2f(((const u16*)p)[i]) : ((const float*)p)[i];
}

// param table: W1,atts1,attd1,We1,atte1,b1,g1,be1,W2,atts2,attd2,We2,atte2,b2,g2,be2,Wout,bout
__device__ __constant__ int dPO[19] = {0,16384,16640,16896,20992,21248,21504,21760,22016,
                                       87552,87808,88064,92160,92416,92672,92928,93184,93440,93441};
static const int hPO[19] = {0,16384,16640,16896,20992,21248,21504,21760,22016,
                            87552,87808,88064,92160,92416,92672,92928,93184,93440,93441};
#define TOTP 93441

// ---------------- prep0: zero workspace zone + dtype detect, one dispatch ----------------
__global__ __launch_bounds__(256) void prep0(unsigned* __restrict__ zp, long nwords,
                                             const unsigned* __restrict__ xbits,
                                             int* __restrict__ flag) {
    if (blockIdx.x < 128) {
        long i = (long)blockIdx.x * 256 + threadIdx.x;
        long stride = 128L * 256;
        for (; i < nwords; i += stride) zp[i] = 0u;
    } else {
        __shared__ int cnt;
        if (threadIdx.x == 0) cnt = 0;
        __syncthreads();
        int sane = 0;
        for (int i = threadIdx.x; i < 1024; i += 256) {
            unsigned lo = xbits[i] & 0xffffu;
            int e = (int)((lo >> 7) & 0xff);
            if (e >= 117 && e <= 133) sane++;
        }
        atomicAdd(&cnt, sane);
        __syncthreads();
        if (threadIdx.x == 0) *flag = (cnt >= 512) ? 1 : 0;
    }
}

// ---------------- param_prep: all input conversion + weight prep + edge_deg ----------------
struct Ptrs18 { const void* s[18]; };

#define NB_XB 512
#define NB_WT1 64
#define NB_WT2 256
#define NB_PALL ((TOTP + 255) / 256)
#define NB_DEG ((NEDGES + 255) / 256)
#define JB1 (NB_XB)
#define JB2 (JB1 + NB_WT1)
#define JB3 (JB2 + NB_WT2)
#define JB4 (JB3 + NB_PALL)
#define JB5 (JB4 + 1)
#define JB6 (JB5 + 1)
#define JB7 (JB6 + 4)
#define NB_PREP (JB7 + NB_DEG)

__global__ __launch_bounds__(256) void param_prep(
    Ptrs18 pp, const void* __restrict__ x_raw, const int* __restrict__ edst,
    const int* __restrict__ flag,
    u16* __restrict__ xb, u16* __restrict__ pall,
    u16* __restrict__ WT1, u16* __restrict__ WT2,
    float* __restrict__ ve1, float* __restrict__ ve2,
    float* __restrict__ us1, float* __restrict__ ud1,
    float* __restrict__ us2, float* __restrict__ ud2,
    int* __restrict__ deg) {
    int b = blockIdx.x, t = threadIdx.x;
    if (b >= JB7) {  // edge_deg histogram
        int e = (b - JB7) * 256 + t;
        if (e < NEDGES) atomicAdd(&deg[edst[e]], 1);
        return;
    }
    int bf = *flag;
    if (b < JB1) {  // x -> xb (octet-vectorized)
        long no = (long)NNODES * 64 / 8;
        long i = (long)b * 256 + t;
        long stride = (long)NB_XB * 256;
        if (bf) {
            const uint4* s = (const uint4*)x_raw;
            uint4* d = (uint4*)xb;
            for (; i < no; i += stride) d[i] = s[i];
        } else {
            const float4* s = (const float4*)x_raw;
            uint4* d = (uint4*)xb;
            for (; i < no; i += stride) {
                float4 a = s[i * 2], c = s[i * 2 + 1];
                uint4 o;
                o.x = (unsigned)f2b(a.x) | ((unsigned)f2b(a.y) << 16);
                o.y = (unsigned)f2b(a.z) | ((unsigned)f2b(a.w) << 16);
                o.z = (unsigned)f2b(c.x) | ((unsigned)f2b(c.y) << 16);
                o.w = (unsigned)f2b(c.z) | ((unsigned)f2b(c.w) << 16);
                d[i] = o;
            }
        }
        return;
    }
    if (b < JB2) {  // WT1: W1[64][256] -> [256][64]
        int i = (b - JB1) * 256 + t;
        int k = i >> 8, c = i & 255;
        WT1[c * 64 + k] = bf ? ((const u16*)pp.s[0])[i] : f2b(((const float*)pp.s[0])[i]);
        return;
    }
    if (b < JB3) {  // WT2: W2[256][256] -> [256][256]
        int i = (b - JB2) * 256 + t;
        int k = i >> 8, c = i & 255;
        WT2[c * 256 + k] = bf ? ((const u16*)pp.s[8])[i] : f2b(((const float*)pp.s[8])[i]);
        return;
    }
    if (b < JB4) {  // pall conversion (bias/g/be/Wout/bout consumers)
        int i = (b - JB3) * 256 + t;
        if (i >= TOTP) return;
        int idx = 0;
        #pragma unroll
        for (int j = 1; j < 18; j++) idx += (i >= dPO[j]) ? 1 : 0;
        int rel = i - dPO[idx];
        pall[i] = bf ? ((const u16*)pp.s[idx])[rel] : f2b(((const float*)pp.s[idx])[rel]);
        return;
    }
    if (b < JB5) {  // ve1 / ve2 from raw We, atte
        if (t < 128) {
            int i = t & 63;
            int f = i >> 2, h = i & 3;
            const void* W = (t < 64) ? pp.s[3] : pp.s[11];
            const void* A = (t < 64) ? pp.s[4] : pp.s[12];
            float* o = (t < 64) ? ve1 : ve2;
            float s = 0.f;
            for (int c = 0; c < 64; c++)
                s += rdp(W, f * 256 + h * 64 + c, bf) * rdp(A, h * 64 + c, bf);
            o[i] = s;
        }
        return;
    }
    if (b < JB6) {  // us1/ud1 from raw W1, atts1, attd1 (256 entries)
        int f = t >> 2, h = t & 3;
        float sa = 0.f, sb = 0.f;
        for (int c = 0; c < 64; c++) {
            float w = rdp(pp.s[0], f * 256 + h * 64 + c, bf);
            sa += w * rdp(pp.s[1], h * 64 + c, bf);
            sb += w * rdp(pp.s[2], h * 64 + c, bf);
        }
        us1[t] = sa;
        ud1[t] = sb;
        return;
    }
    {  // us2/ud2 from raw W2, atts2, attd2 (1024 entries, exactly 4 blocks)
        int i = (b - JB6) * 256 + t;
        if (i >= 1024) return;
        int f = i >> 2, h = i & 3;
        float sa = 0.f, sb = 0.f;
        for (int c = 0; c < 64; c++) {
            float w = rdp(pp.s[8], f * 256 + h * 64 + c, bf);
            sa += w * rdp(pp.s[9], h * 64 + c, bf);
            sb += w * rdp(pp.s[10], h * 64 + c, bf);
        }
        us2[i] = sa;
        ud2[i] = sb;
    }
}

// ---------------- CSR: per-256-block sums ----------------
__global__ void block_sum(const int* __restrict__ deg, int* __restrict__ bsums, int n) {
    __shared__ int lds[256];
    int i = blockIdx.x * 256 + threadIdx.x;
    lds[threadIdx.x] = (i < n) ? deg[i] : 0;
    __syncthreads();
    for (int s = 128; s; s >>= 1) {
        if (threadIdx.x < s) lds[threadIdx.x] += lds[threadIdx.x + s];
        __syncthreads();
    }
    if (threadIdx.x == 0) bsums[blockIdx.x] = lds[0];
}

// ---------------- CSR: fused block-prefix scan + offset write ----------------
__global__ void scan_write(const int* __restrict__ bsums, const int* __restrict__ deg,
                           int* __restrict__ off, int* __restrict__ cursor, int n, int nb) {
    __shared__ int sb[256];
    __shared__ int lds[256];
    int t = threadIdx.x;
    int v = (t < nb) ? bsums[t] : 0;
    sb[t] = v;
    __syncthreads();
    for (int s = 1; s < 256; s <<= 1) {
        int u = (t >= s) ? sb[t - s] : 0;
        __syncthreads();
        sb[t] += u;
        __syncthreads();
    }
    int boff = sb[blockIdx.x] - bsums[blockIdx.x];  // exclusive prefix of this block
    int i = blockIdx.x * 256 + t;
    int dv = (i < n) ? deg[i] : 0;
    lds[t] = dv;
    __syncthreads();
    for (int s = 1; s < 256; s <<= 1) {
        int u = (t >= s) ? lds[t - s] : 0;
        __syncthreads();
        lds[t] += u;
        __syncthreads();
    }
    int exc = lds[t] - dv + boff;
    if (i < n) { off[i] = exc; cursor[i] = exc; }
}

// ---------------- edge stage: one 32B record per edge, scattered once ----------------
__global__ __launch_bounds__(256) void edge_stage(
    const void* __restrict__ eattr_raw, const int* __restrict__ flag,
    const int* __restrict__ esrc, const int* __restrict__ edst,
    const float* __restrict__ ve1, const float* __restrict__ ve2,
    int* __restrict__ cursor, uint4* __restrict__ rec) {
    int e = blockIdx.x * 256 + threadIdx.x;
    if (e >= NEDGES) return;
    float a[16];
    if (*flag) {
        const u16* s = (const u16*)eattr_raw + (long)e * 16;
        const uint4* q = (const uint4*)s;
        uint4 q0 = q[0], q1 = q[1];
        unsigned w0[8] = {q0.x, q0.y, q0.z, q0.w, q1.x, q1.y, q1.z, q1.w};
        #pragma unroll
        for (int j = 0; j < 8; j++) {
            a[2 * j] = b2f((u16)(w0[j] & 0xffff));
            a[2 * j + 1] = b2f((u16)(w0[j] >> 16));
        }
    } else {
        const float* s = (const float*)eattr_raw + (long)e * 16;
        #pragma unroll
        for (int j = 0; j < 16; j += 4) {
            float4 q = *(const float4*)(s + j);
            a[j] = q.x; a[j + 1] = q.y; a[j + 2] = q.z; a[j + 3] = q.w;
        }
    }
    float s1[4], s2[4];
    #pragma unroll
    for (int h = 0; h < 4; h++) {
        float t1 = 0.f, t2 = 0.f;
        #pragma unroll
        for (int f = 0; f < 16; f++) {
            t1 += a[f] * ve1[f * 4 + h];
            t2 += a[f] * ve2[f * 4 + h];
        }
        s1[h] = t1;
        s2[h] = t2;
    }
    unsigned a1lo = (unsigned)f2b(s1[0]) | ((unsigned)f2b(s1[1]) << 16);
    unsigned a1hi = (unsigned)f2b(s1[2]) | ((unsigned)f2b(s1[3]) << 16);
    unsigned a2lo = (unsigned)f2b(s2[0]) | ((unsigned)f2b(s2[1]) << 16);
    unsigned a2hi = (unsigned)f2b(s2[2]) | ((unsigned)f2b(s2[3]) << 16);
    int d = edst[e];
    int p = atomicAdd(&cursor[d], 1);
    unsigned src = (unsigned)esrc[e];
    rec[(long)p * 2 + 0] = make_uint4(src, a1lo, a1hi, 0u);
    rec[(long)p * 2 + 1] = make_uint4(src, a2lo, a2hi, 0u);
}

// ---------------- tiled MFMA GEMM (optional fused BN+ReLU on A fragments) ----------------
__device__ __forceinline__ void gload_lds16(const u16* g, u16* l) {
    __builtin_amdgcn_global_load_lds(
        (const __attribute__((address_space(1))) unsigned*)g,
        (__attribute__((address_space(3))) unsigned*)l, 16, 0, 0);
}

template <int K, bool BN>
__global__ __launch_bounds__(256) void gemm_tile(const u16* __restrict__ A,
                                                 const u16* __restrict__ WT,
                                                 const float* __restrict__ coef,
                                                 u16* __restrict__ out) {
    __shared__ u16 As[128 * 32];
    __shared__ u16 Bs[128 * 32];
    int tid = threadIdx.x;
    int wave = tid >> 6, lane = tid & 63;
    int wr = wave >> 1, wc = wave & 1;
    int quad = lane >> 4, l15 = lane & 15;
    long row0 = (long)(blockIdx.x >> 1) * 128;
    int col0 = (blockIdx.x & 1) * 128;
    int srow = lane >> 2;
    int soct = (lane & 3) * 8;
    f32x4 acc[4][4] = {};
    for (int kk = 0; kk < K; kk += 32) {
        #pragma unroll
        for (int sub = 0; sub < 2; sub++) {
            int rr = wave * 32 + sub * 16;
            long gr = row0 + rr + srow;
            if (gr >= NNODES) gr = NNODES - 1;
            gload_lds16(A + gr * K + kk + soct, &As[rr * 32]);
            gload_lds16(WT + (long)(col0 + rr + srow) * K + kk + soct, &Bs[rr * 32]);
        }
        __syncthreads();
        bf16x8 av[4], bv[4];
        #pragma unroll
        for (int m = 0; m < 4; m++)
            av[m] = *(const bf16x8*)&As[(wr * 64 + m * 16 + l15) * 32 + quad * 8];
        if (BN) {
            int kb = kk + quad * 8;
            float4 sc0 = *(const float4*)(coef + kb);
            float4 sc1 = *(const float4*)(coef + kb + 4);
            float4 sh0 = *(const float4*)(coef + 256 + kb);
            float4 sh1 = *(const float4*)(coef + 256 + kb + 4);
            float scl[8] = {sc0.x, sc0.y, sc0.z, sc0.w, sc1.x, sc1.y, sc1.z, sc1.w};
            float shf[8] = {sh0.x, sh0.y, sh0.z, sh0.w, sh1.x, sh1.y, sh1.z, sh1.w};
            #pragma unroll
            for (int m = 0; m < 4; m++) {
                #pragma unroll
                for (int j = 0; j < 8; j++) {
                    float v = b2f((u16)av[m][j]);
                    v = fmaxf(v * scl[j] + shf[j], 0.f);
                    av[m][j] = (short)f2b(v);
                }
            }
        }
        #pragma unroll
        for (int n = 0; n < 4; n++)
            bv[n] = *(const bf16x8*)&Bs[(wc * 64 + n * 16 + l15) * 32 + quad * 8];
        #pragma unroll
        for (int m = 0; m < 4; m++)
            #pragma unroll
            for (int n = 0; n < 4; n++)
                acc[m][n] = __builtin_amdgcn_mfma_f32_16x16x32_bf16(av[m], bv[n],
                                                                    acc[m][n], 0, 0, 0);
        __syncthreads();
    }
    #pragma unroll
    for (int m = 0; m < 4; m++) {
        #pragma unroll
        for (int j = 0; j < 4; j++) {
            long r = row0 + wr * 64 + m * 16 + quad * 4 + j;
            if (r < NNODES) {
                u16* op = out + r * HC + col0 + wc * 64 + l15;
                #pragma unroll
                for (int n = 0; n < 4; n++) op[n * 16] = f2b(acc[m][n][j]);
            }
        }
    }
}

// ---------------- a_s/a_d projection, vectorized uint2 loads ----------------
template <int K, bool BN>
__global__ __launch_bounds__(256) void proj_att(const u16* __restrict__ X,
                                                const float* __restrict__ coef,
                                                const float* __restrict__ us,
                                                const float* __restrict__ ud,
                                                float* __restrict__ as_, float* __restrict__ ad_) {
    int gw = (blockIdx.x * 256 + threadIdx.x) >> 6;
    int lane = threadIdx.x & 63;
    int node, f0;
    if (K == 64) {
        node = gw * 4 + (lane >> 4);
        f0 = (lane & 15) * 4;
    } else {
        node = gw;
        f0 = lane * 4;
    }
    if (node >= NNODES) return;
    uint2 v = *(const uint2*)(X + (long)node * K + f0);
    float xv[4] = {b2f((u16)(v.x & 0xffffu)), b2f((u16)(v.x >> 16)),
                   b2f((u16)(v.y & 0xffffu)), b2f((u16)(v.y >> 16))};
    float pas[4] = {0.f, 0.f, 0.f, 0.f}, pad[4] = {0.f, 0.f, 0.f, 0.f};
    #pragma unroll
    for (int j = 0; j < 4; j++) {
        int f = f0 + j;
        float x = xv[j];
        if (BN) x = fmaxf(x * coef[f] + coef[256 + f], 0.f);
        #pragma unroll
        for (int h = 0; h < 4; h++) {
            pas[h] += x * us[f * 4 + h];
            pad[h] += x * ud[f * 4 + h];
        }
    }
    const int omax = (K == 64) ? 8 : 32;
    #pragma unroll
    for (int h = 0; h < 4; h++) {
        for (int o = omax; o; o >>= 1) {
            pas[h] += __shfl_xor(pas[h], o);
            pad[h] += __shfl_xor(pad[h], o);
        }
    }
    bool wr = (K == 64) ? ((lane & 15) == 0) : (lane == 0);
    if (wr) {
        #pragma unroll
        for (int h = 0; h < 4; h++) {
            as_[node * 4 + h] = pas[h];
            ad_[node * 4 + h] = pad[h];
        }
    }
}

// ---------------- fused GAT attention, one wave per dst node ----------------
__global__ __launch_bounds__(256) void gat_fused(
    const u16* __restrict__ xs, const float* __restrict__ as_, const float* __restrict__ ad_,
    const uint4* __restrict__ rec, int layer,
    const int* __restrict__ off, const int* __restrict__ deg,
    const u16* __restrict__ bias, u16* __restrict__ out) {
    __shared__ int s_lds[4][64];
    __shared__ float w_lds[4][64][4];
    int wid = (blockIdx.x * 256 + threadIdx.x) >> 6;
    if (wid >= NNODES) return;
    int wave = threadIdx.x >> 6;
    int lane = threadIdx.x & 63;
    int d = wid;
    int st = off[d], dg = deg[d];
    int slot = lane >> 2, h = lane & 3;
    float adv = ad_[d * 4 + h];
    float m = -1e30f, s = 0.f, sae = 0.f;
    const uint4* rbase = rec + (long)st * 2 + layer;

    if (dg <= 64) {
        for (int i = slot; i < dg; i += 16) {
            uint4 r4 = rbase[(long)i * 2];
            int src = (int)r4.x;
            unsigned wsel = (h & 2) ? r4.z : r4.y;
            float aev = b2f((u16)((h & 1) ? (wsel >> 16) : (wsel & 0xffffu)));
            float t = as_[src * 4 + h] + adv + aev;
            float lg = (t > 0.f) ? t : 0.2f * t;
            if (h == 0) s_lds[wave][i] = src;
            w_lds[wave][i][h] = lg;
            sae += aev;
            float mn = fmaxf(m, lg);
            s = s * __expf(m - mn) + __expf(lg - mn);
            m = mn;
        }
        #pragma unroll
        for (int o = 4; o < 64; o <<= 1) {
            float mo = __shfl_xor(m, o), so = __shfl_xor(s, o), ao = __shfl_xor(sae, o);
            float mn = fmaxf(m, mo);
            s = s * __expf(m - mn) + so * __expf(mo - mn);
            m = mn;
            sae += ao;
        }
        float invs, wself;
        {
            float asv = as_[d * 4 + h];
            float l0 = asv + adv + sae / fmaxf((float)dg, 1.f);
            l0 = (l0 > 0.f) ? l0 : 0.2f * l0;
            float mn = fmaxf(m, l0);
            s = s * __expf(m - mn) + __expf(l0 - mn);
            m = mn;
            invs = 1.f / s;
            wself = __expf(l0 - mn) * invs;
        }
        for (int i = slot; i < dg; i += 16)
            w_lds[wave][i][h] = __expf(w_lds[wave][i][h] - m) * invs;

        int cg = lane & 31, half = lane >> 5;
        int ch8 = cg * 8;
        int h2 = cg >> 3;
        float ws2 = __shfl(wself, h2);
        const u16* xbase = xs + ch8;
        float a0, a1, a2, a3, a4, a5, a6, a7;
        {
            uint4 v = *(const uint4*)(xbase + (long)d * HC);
            float wsf = half ? 0.f : ws2;
            a0 = wsf * b2f((u16)(v.x & 0xffffu)); a1 = wsf * b2f((u16)(v.x >> 16));
            a2 = wsf * b2f((u16)(v.y & 0xffffu)); a3 = wsf * b2f((u16)(v.y >> 16));
            a4 = wsf * b2f((u16)(v.z & 0xffffu)); a5 = wsf * b2f((u16)(v.z >> 16));
            a6 = wsf * b2f((u16)(v.w & 0xffffu)); a7 = wsf * b2f((u16)(v.w >> 16));
        }
        int i = half;
        for (; i + 6 < dg; i += 8) {
            float wA = w_lds[wave][i][h2];     int sA = s_lds[wave][i];
            float wB = w_lds[wave][i + 2][h2]; int sB = s_lds[wave][i + 2];
            float wC = w_lds[wave][i + 4][h2]; int sC = s_lds[wave][i + 4];
            float wD = w_lds[wave][i + 6][h2]; int sD = s_lds[wave][i + 6];
            uint4 vA = *(const uint4*)(xbase + (long)sA * HC);
            uint4 vB = *(const uint4*)(xbase + (long)sB * HC);
            uint4 vC = *(const uint4*)(xbase + (long)sC * HC);
            uint4 vD = *(const uint4*)(xbase + (long)sD * HC);
            a0 += wA * b2f((u16)(vA.x & 0xffffu)) + wB * b2f((u16)(vB.x & 0xffffu))
                + wC * b2f((u16)(vC.x & 0xffffu)) + wD * b2f((u16)(vD.x & 0xffffu));
            a1 += wA * b2f((u16)(vA.x >> 16))     + wB * b2f((u16)(vB.x >> 16))
                + wC * b2f((u16)(vC.x >> 16))     + wD * b2f((u16)(vD.x >> 16));
            a2 += wA * b2f((u16)(vA.y & 0xffffu)) + wB * b2f((u16)(vB.y & 0xffffu))
                + wC * b2f((u16)(vC.y & 0xffffu)) + wD * b2f((u16)(vD.y & 0xffffu));
            a3 += wA * b2f((u16)(vA.y >> 16))     + wB * b2f((u16)(vB.y >> 16))
                + wC * b2f((u16)(vC.y >> 16))     + wD * b2f((u16)(vD.y >> 16));
            a4 += wA * b2f((u16)(vA.z & 0xffffu)) + wB * b2f((u16)(vB.z & 0xffffu))
                + wC * b2f((u16)(vC.z & 0xffffu)) + wD * b2f((u16)(vD.z & 0xffffu));
            a5 += wA * b2f((u16)(vA.z >> 16))     + wB * b2f((u16)(vB.z >> 16))
                + wC * b2f((u16)(vC.z >> 16))     + wD * b2f((u16)(vD.z >> 16));
            a6 += wA * b2f((u16)(vA.w & 0xffffu)) + wB * b2f((u16)(vB.w & 0xffffu))
                + wC * b2f((u16)(vC.w & 0xffffu)) + wD * b2f((u16)(vD.w & 0xffffu));
            a7 += wA * b2f((u16)(vA.w >> 16))     + wB * b2f((u16)(vB.w >> 16))
                + wC * b2f((u16)(vC.w >> 16))     + wD * b2f((u16)(vD.w >> 16));
        }
        for (; i < dg; i += 2) {
            float wA = w_lds[wave][i][h2]; int sA = s_lds[wave][i];
            uint4 vA = *(const uint4*)(xbase + (long)sA * HC);
            a0 += wA * b2f((u16)(vA.x & 0xffffu)); a1 += wA * b2f((u16)(vA.x >> 16));
            a2 += wA * b2f((u16)(vA.y & 0xffffu)); a3 += wA * b2f((u16)(vA.y >> 16));
            a4 += wA * b2f((u16)(vA.z & 0xffffu)); a5 += wA * b2f((u16)(vA.z >> 16));
            a6 += wA * b2f((u16)(vA.w & 0xffffu)); a7 += wA * b2f((u16)(vA.w >> 16));
        }
        a0 += __shfl_xor(a0, 32); a1 += __shfl_xor(a1, 32);
        a2 += __shfl_xor(a2, 32); a3 += __shfl_xor(a3, 32);
        a4 += __shfl_xor(a4, 32); a5 += __shfl_xor(a5, 32);
        a6 += __shfl_xor(a6, 32); a7 += __shfl_xor(a7, 32);
        if (half == 0) {
            uint4 bv = *(const uint4*)(bias + ch8);
            a0 += b2f((u16)(bv.x & 0xffffu)); a1 += b2f((u16)(bv.x >> 16));
            a2 += b2f((u16)(bv.y & 0xffffu)); a3 += b2f((u16)(bv.y >> 16));
            a4 += b2f((u16)(bv.z & 0xffffu)); a5 += b2f((u16)(bv.z >> 16));
            a6 += b2f((u16)(bv.w & 0xffffu)); a7 += b2f((u16)(bv.w >> 16));
            uint4 ov;
            ov.x = (unsigned)f2b(a0) | ((unsigned)f2b(a1) << 16);
            ov.y = (unsigned)f2b(a2) | ((unsigned)f2b(a3) << 16);
            ov.z = (unsigned)f2b(a4) | ((unsigned)f2b(a5) << 16);
            ov.w = (unsigned)f2b(a6) | ((unsigned)f2b(a7) << 16);
            *(uint4*)(out + (long)d * HC + ch8) = ov;
        }
        return;
    }

    // ---------- fallback path (deg > 64): exact ----------
    for (int base = 0; base < dg; base += 16) {
        int i = base + slot;
        float lg = -1e30f, aev = 0.f, w = 0.f;
        if (i < dg) {
            uint4 r4 = rbase[(long)i * 2];
            int src = (int)r4.x;
            unsigned wsel = (h & 2) ? r4.z : r4.y;
            aev = b2f((u16)((h & 1) ? (wsel >> 16) : (wsel & 0xffffu)));
            float t = as_[src * 4 + h] + adv + aev;
            lg = (t > 0.f) ? t : 0.2f * t;
        }
        sae += aev;
        float mn = fmaxf(m, lg);
        if (i < dg) w = __expf(lg - mn);
        s = s * __expf(m - mn) + w;
        m = mn;
    }
    #pragma unroll
    for (int o = 4; o < 64; o <<= 1) {
        float mo = __shfl_xor(m, o), so = __shfl_xor(s, o), ao = __shfl_xor(sae, o);
        float mn = fmaxf(m, mo);
        s = s * __expf(m - mn) + so * __expf(mo - mn);
        m = mn;
        sae += ao;
    }
    float invs, wself;
    {
        float asv = as_[d * 4 + h];
        float l0 = asv + adv + sae / fmaxf((float)dg, 1.f);
        l0 = (l0 > 0.f) ? l0 : 0.2f * l0;
        float mn = fmaxf(m, l0);
        s = s * __expf(m - mn) + __expf(l0 - mn);
        m = mn;
        invs = 1.f / s;
        wself = __expf(l0 - mn) * invs;
    }
    int h2 = lane >> 4;
    float m2 = __shfl(m, h2);
    float is2 = __shfl(invs, h2);
    float ws2 = __shfl(wself, h2);
    float adv2 = __shfl(adv, h2);
    int cb = lane * 4;
    float a0, a1, a2, a3;
    {
        uint2 v = *(const uint2*)(xs + (long)d * HC + cb);
        a0 = ws2 * b2f((u16)(v.x & 0xffffu)); a1 = ws2 * b2f((u16)(v.x >> 16));
        a2 = ws2 * b2f((u16)(v.y & 0xffffu)); a3 = ws2 * b2f((u16)(v.y >> 16));
    }
    int slot16 = lane & 15;
    int lhi = lane & 48;
    for (int base = 0; base < dg; base += 16) {
        int cnt = min(16, dg - base);
        float wv = 0.f;
        int srcl = 0;
        if (slot16 < cnt) {
            uint4 r4 = rbase[(long)(base + slot16) * 2];
            srcl = (int)r4.x;
            unsigned wsel = (h2 & 2) ? r4.z : r4.y;
            float aev = b2f((u16)((h2 & 1) ? (wsel >> 16) : (wsel & 0xffffu)));
            float t = as_[srcl * 4 + h2] + adv2 + aev;
            t = (t > 0.f) ? t : 0.2f * t;
            wv = __expf(t - m2) * is2;
        }
        for (int j = 0; j < cnt; j++) {
            float w0 = __shfl(wv, lhi | j);
            int s0 = __shfl(srcl, j);
            uint2 v0 = *(const uint2*)(xs + (long)s0 * HC + cb);
            a0 += w0 * b2f((u16)(v0.x & 0xffffu));
            a1 += w0 * b2f((u16)(v0.x >> 16));
            a2 += w0 * b2f((u16)(v0.y & 0xffffu));
            a3 += w0 * b2f((u16)(v0.y >> 16));
        }
    }
    u16 o0 = f2b(a0 + b2f(bias[cb + 0]));
    u16 o1 = f2b(a1 + b2f(bias[cb + 1]));
    u16 o2 = f2b(a2 + b2f(bias[cb + 2]));
    u16 o3 = f2b(a3 + b2f(bias[cb + 3]));
    uint2 ov;
    ov.x = (unsigned)o0 | ((unsigned)o1 << 16);
    ov.y = (unsigned)o2 | ((unsigned)o3 << 16);
    *(uint2*)(out + (long)d * HC + cb) = ov;
}

// ---------------- BatchNorm stats + last-block coef finalize ----------------
__global__ __launch_bounds__(256) void bn_stats(const u16* __restrict__ h,
                                                float* __restrict__ stats,
                                                int* __restrict__ cnt,
                                                const u16* __restrict__ g,
                                                const u16* __restrict__ be,
                                                float* __restrict__ coef) {
    __shared__ float lsum[256], lsq[256];
    __shared__ int last;
    int t = threadIdx.x;
    int p = t & 127;
    int ro = t >> 7;
    float s0 = 0.f, q0 = 0.f, s1 = 0.f, q1 = 0.f;
    for (int r = blockIdx.x * 2 + ro; r < NNODES; r += gridDim.x * 2) {
        unsigned v = *(const unsigned*)(h + (long)r * HC + 2 * p);
        float lo = b2f((u16)(v & 0xffffu)), hi = b2f((u16)(v >> 16));
        s0 += lo; q0 += lo * lo;
        s1 += hi; q1 += hi * hi;
    }
    if (ro == 1) {
        lsum[2 * p] = s0; lsum[2 * p + 1] = s1;
        lsq[2 * p] = q0;  lsq[2 * p + 1] = q1;
    }
    __syncthreads();
    if (ro == 0) {
        atomicAdd(&stats[2 * p],           s0 + lsum[2 * p]);
        atomicAdd(&stats[2 * p + 1],       s1 + lsum[2 * p + 1]);
        atomicAdd(&stats[256 + 2 * p],     q0 + lsq[2 * p]);
        atomicAdd(&stats[256 + 2 * p + 1], q1 + lsq[2 * p + 1]);
    }
    // last-block finalize (replaces bn_coef dispatch)
    __threadfence();
    __syncthreads();
    if (t == 0) {
        int old = atomicAdd(cnt, 1);
        last = (old == (int)gridDim.x - 1);
    }
    __syncthreads();
    if (last) {
        float sum = atomicAdd(&stats[t], 0.f);       // atomic read: L2-coherent
        float sq  = atomicAdd(&stats[256 + t], 0.f);
        float mu = sum * (1.0f / NNODES);
        float var = sq * (1.0f / NNODES) - mu * mu;
        var = fmaxf(var, 0.f);
        float rs = rsqrtf(var + 1e-5f);
        float sc = b2f(g[t]) * rs;
        coef[t] = sc;
        coef[256 + t] = b2f(be[t]) - sc * mu;
    }
}

// ---------------- output head (+fused BN2+ReLU), vectorized ----------------
__global__ __launch_bounds__(256) void out_head(const u16* __restrict__ h,
                                                const float* __restrict__ coef,
                                                const u16* __restrict__ wout,
                                                const u16* __restrict__ bout,
                                                void* __restrict__ y,
                                                const int* __restrict__ flag) {
    int wid = (blockIdx.x * 256 + threadIdx.x) >> 6;
    int lane = threadIdx.x & 63;
    if (wid >= NNODES) return;
    int c0 = lane * 4;
    uint2 v = *(const uint2*)(h + (long)wid * HC + c0);
    uint2 wv = *(const uint2*)(wout + c0);
    float hv[4] = {b2f((u16)(v.x & 0xffffu)), b2f((u16)(v.x >> 16)),
                   b2f((u16)(v.y & 0xffffu)), b2f((u16)(v.y >> 16))};
    float wf[4] = {b2f((u16)(wv.x & 0xffffu)), b2f((u16)(wv.x >> 16)),
                   b2f((u16)(wv.y & 0xffffu)), b2f((u16)(wv.y >> 16))};
    float p = 0.f;
    #pragma unroll
    for (int j = 0; j < 4; j++) {
        float t = fmaxf(hv[j] * coef[c0 + j] + coef[256 + c0 + j], 0.f);
        p += t * wf[j];
    }
    for (int o = 32; o; o >>= 1) p += __shfl_down(p, o);
    if (lane == 0) {
        float t = p + b2f(bout[0]);
        if (*flag) ((u16*)y)[wid] = f2b(t);
        else       ((float*)y)[wid] = t;
    }
}

extern "C" void kernel_launch(void* const* d_in, const int* in_sizes, int n_in,
                              void* d_out, int out_size, void* d_ws, size_t ws_size,
                              hipStream_t stream) {
    (void)in_sizes; (void)n_in; (void)out_size; (void)ws_size;
    const void* x_raw     = d_in[0];
    const int*  esrc      = (const int*)d_in[1];
    const int*  edst      = (const int*)d_in[2];
    const void* eattr_raw = d_in[3];

    char* ws = (char*)d_ws;
    size_t o = 0;
    auto alloc = [&](size_t bytes) -> char* {
        o = (o + 255) & ~(size_t)255;
        char* p = ws + o;
        o += bytes;
        return p;
    };
    int* dflag = (int*)alloc(256);
    u16* xb   = (u16*)alloc((size_t)NNODES * 64 * 2);
    u16* pall = (u16*)alloc((size_t)TOTP * 2);
    u16 *b1b = pall + hPO[5], *g1b = pall + hPO[6], *be1b = pall + hPO[7],
        *b2b = pall + hPO[13], *g2b = pall + hPO[14], *be2b = pall + hPO[15],
        *Woutb = pall + hPO[16], *boutb = pall + hPO[17];
    u16* WT1 = (u16*)alloc(256 * 64 * 2);
    u16* WT2 = (u16*)alloc(256 * 256 * 2);
    float* ve1 = (float*)alloc(64 * 4);
    float* ve2 = (float*)alloc(64 * 4);
    float* us1 = (float*)alloc(256 * 4);
    float* ud1 = (float*)alloc(256 * 4);
    float* us2 = (float*)alloc(1024 * 4);
    float* ud2 = (float*)alloc(1024 * 4);
    float* coef1 = (float*)alloc(512 * 4);
    float* coef2 = (float*)alloc(512 * 4);
    // zero zone: deg + stats + bn counters
    int* deg = (int*)alloc((size_t)NNODES * 4);
    float* stats1 = (float*)alloc(512 * 4);
    float* stats2 = (float*)alloc(512 * 4);
    int* bnc1 = (int*)alloc(256);
    int* bnc2 = (int*)alloc(256);
    size_t zero_end = o;
    size_t zero_begin = (size_t)((char*)deg - ws);
    // rest
    int* off = (int*)alloc((size_t)NNODES * 4);
    int* cursor = (int*)alloc((size_t)NNODES * 4);
    int* bsums = (int*)alloc(256 * 4);
    uint4* rec = (uint4*)alloc((size_t)NEDGES * 32);
    float* as_ = (float*)alloc((size_t)NNODES * 16);
    float* ad_ = (float*)alloc((size_t)NNODES * 16);
    u16* bufA = (u16*)alloc((size_t)NNODES * HC * 2);  // xs1, then xs2
    u16* bufB = (u16*)alloc((size_t)NNODES * HC * 2);  // h1raw, then h2raw

    long zwords = (long)((zero_end - zero_begin) / 4);
    prep0<<<129, 256, 0, stream>>>((unsigned*)(ws + zero_begin), zwords,
                                   (const unsigned*)x_raw, dflag);

    Ptrs18 pp;
    for (int i = 0; i < 18; i++) pp.s[i] = d_in[4 + i];
    param_prep<<<NB_PREP, 256, 0, stream>>>(pp, x_raw, edst, dflag, xb, pall, WT1, WT2,
                                            ve1, ve2, us1, ud1, us2, ud2, deg);

    int eblocks = (NEDGES + 255) / 256;
    int nb = (NNODES + 255) / 256;  // 196
    block_sum<<<nb, 256, 0, stream>>>(deg, bsums, NNODES);
    scan_write<<<nb, 256, 0, stream>>>(bsums, deg, off, cursor, NNODES, nb);
    edge_stage<<<eblocks, 256, 0, stream>>>(eattr_raw, dflag, esrc, edst, ve1, ve2,
                                            cursor, rec);

    int gtiles = ((NNODES + 127) / 128) * 2;  // 782
    int wblocks = (NNODES * 64 + 255) / 256;  // 12500 (1 wave per node)
    int pblocks64 = (NNODES + 15) / 16;       // 3125 (4 nodes per wave)

    // layer 1 (xb: K=64)
    gemm_tile<64, false><<<gtiles, 256, 0, stream>>>(xb, WT1, nullptr, bufA);
    proj_att<64, false><<<pblocks64, 256, 0, stream>>>(xb, nullptr, us1, ud1, as_, ad_);
    gat_fused<<<wblocks, 256, 0, stream>>>(bufA, as_, ad_, rec, 0, off, deg, b1b, bufB);
    bn_stats<<<256, 256, 0, stream>>>(bufB, stats1, bnc1, g1b, be1b, coef1);

    // layer 2: BN1 fused into GEMM A-path and proj_att
    gemm_tile<256, true><<<gtiles, 256, 0, stream>>>(bufB, WT2, coef1, bufA);
    proj_att<256, true><<<wblocks, 256, 0, stream>>>(bufB, coef1, us2, ud2, as_, ad_);
    gat_fused<<<wblocks, 256, 0, stream>>>(bufA, as_, ad_, rec, 1, off, deg, b2b, bufB);
    bn_stats<<<256, 256, 0, stream>>>(bufB, stats2, bnc2, g2b, be2b, coef2);

    // output head (BN2 fused)
    out_head<<<wblocks, 256, 0, stream>>>(bufB, coef2, Woutb, boutb, d_out, dflag);
}